// Round 14
// baseline (291.821 us; speedup 1.0000x reference)
//
#include <hip/hip_runtime.h>
#include <hip/hip_bf16.h>

// Problem constants
#define BATCH 32
#define LQ 64
#define LD 512
#define EMB 300
#define FFH 100
#define ATTD 32
#define NH 8
#define NK 21
#define MQ (BATCH * LQ)          // 2048 query tokens
#define MD (BATCH * LD)          // 16384 doc tokens
#define MALL (MQ + MD)           // 18432 merged tokens

typedef __attribute__((ext_vector_type(8))) short bf16x8;
typedef __attribute__((ext_vector_type(4))) float f32x4;

__device__ __forceinline__ float wave_sum(float v) {
    #pragma unroll
    for (int off = 32; off > 0; off >>= 1) v += __shfl_xor(v, off);
    return v;
}

__device__ __forceinline__ float bf2f(__hip_bfloat16 h) {
    return __bfloat162float(h);
}

// 4 consecutive bf16 -> float4 (8B-aligned source)
__device__ __forceinline__ float4 bf4_to_f4(const __hip_bfloat16* p) {
    uint2 u = *(const uint2*)p;
    float4 f;
    f.x = __uint_as_float((u.x & 0xffffu) << 16);
    f.y = __uint_as_float(u.x & 0xffff0000u);
    f.z = __uint_as_float((u.y & 0xffffu) << 16);
    f.w = __uint_as_float(u.y & 0xffff0000u);
    return f;
}

__device__ __forceinline__ unsigned short f2bfu(float x) {
    __hip_bfloat16 h = __float2bfloat16(x);
    return *(unsigned short*)&h;
}

// ---------------- fused input prep: xbf = bf16(emb*mask), mall = concat masks ------------
__global__ void maskmul_all(const float* __restrict__ q_embed, const float* __restrict__ d_embed,
                            const float* __restrict__ mask_q, const float* __restrict__ mask_d,
                            __hip_bfloat16* __restrict__ xbf, float* __restrict__ mall) {
    int i = blockIdx.x * blockDim.x + threadIdx.x;
    if (i >= MALL * EMB) return;
    int tok = i / EMB;
    float m, v;
    if (tok < MQ) {
        m = mask_q[tok];
        v = q_embed[i];
    } else {
        m = mask_d[tok - MQ];
        v = d_embed[i - MQ * EMB];
    }
    xbf[i] = __float2bfloat16(v * m);
    if (i % EMB == 0) mall[tok] = m;
}

// ---------------- weights convert/transpose + lpraw zero, one kernel ----------------
// w1t [l][100][300], awt [l][96][300], w2t [l][320][128] zero-padded, owt [l][320][32] padded.
__device__ __forceinline__ void conv_seg(const float* __restrict__ w, __hip_bfloat16* __restrict__ wt,
                                         int j, int K, int N) {
    int l = j / (K * N);
    int r = j % (K * N);
    int k = r / N, n = r % N;
    wt[(size_t)l * N * K + (size_t)n * K + k] = __float2bfloat16(w[j]);
}
__global__ void convert_all(const float* __restrict__ w1, const float* __restrict__ w2,
                            const float* __restrict__ aw, const float* __restrict__ ow,
                            __hip_bfloat16* __restrict__ w1t, __hip_bfloat16* __restrict__ w2t,
                            __hip_bfloat16* __restrict__ awt, __hip_bfloat16* __restrict__ owt,
                            float* __restrict__ lpraw) {
    int i = blockIdx.x * blockDim.x + threadIdx.x;
    const int S1 = 2 * EMB * FFH;          // 60000
    const int S2 = S1 + 2 * 320 * 128;     // +81920
    const int S3 = S2 + 2 * EMB * 96;      // +57600
    const int S4 = S3 + 2 * 320 * 32;      // +20480  (= 220000)
    const int S5 = S4 + BATCH * LQ * NK;   // +43008  (= 263008)
    if (i < S1) {
        conv_seg(w1, w1t, i, EMB, FFH);
    } else if (i < S2) {
        int j = i - S1;
        int l = j / (320 * 128);
        int r = j % (320 * 128);
        int n = r / 128, k = r % 128;
        float v = (n < EMB && k < FFH) ? w2[(size_t)l * FFH * EMB + (size_t)k * EMB + n] : 0.f;
        w2t[j] = __float2bfloat16(v);
    } else if (i < S3) {
        conv_seg(aw, awt, i - S2, EMB, 96);
    } else if (i < S4) {
        int j = i - S3;
        int l = j / (320 * 32);
        int r = j % (320 * 32);
        int n = r / 32, k = r % 32;
        float v = (n < EMB && k < ATTD) ? ow[(size_t)l * ATTD * EMB + (size_t)k * EMB + n] : 0.f;
        owt[j] = __float2bfloat16(v);
    } else if (i < S5) {
        lpraw[i - S4] = 0.f;
    }
}

// ---------------- shared staging helper: 8 bf16 of one row ----------------
__device__ __forceinline__ void stage_row8(const __hip_bfloat16* __restrict__ src, bool rowvalid,
                                           int K, int gk, __hip_bfloat16* dst) {
    if (rowvalid && gk + 8 <= K) {
        const uint2* p = (const uint2*)(src + gk);
        uint2 a = p[0], b = p[1];
        *(uint2*)dst = a;
        *(uint2*)(dst + 4) = b;
    } else {
        #pragma unroll
        for (int j = 0; j < 8; j++)
            dst[j] = (rowvalid && gk + j < K) ? src[gk + j] : __float2bfloat16(0.f);
    }
}

// ---------------- MFMA bf16 GEMM: Cb[M,Ns] = A[M,K] @ Bt[Nr,K]^T + bias (+relu) ---------
// 64x64 tile, 4 waves (2x2), 2x2 mfma_f32_16x16x32_bf16 fragments.
// D layout (m89-verified): col = lane&15, row = (lane>>4)*4 + reg.
template <bool RELU>
__global__ __launch_bounds__(256) void gemm_mfma(const __hip_bfloat16* __restrict__ A,
                                                 const __hip_bfloat16* __restrict__ Bt,
                                                 const float* __restrict__ bias,
                                                 __hip_bfloat16* __restrict__ Cb,
                                                 int M, int Nr, int Ns, int K) {
    __shared__ __align__(16) __hip_bfloat16 As[64][40];
    __shared__ __align__(16) __hip_bfloat16 Bs[64][40];
    const int tid = threadIdx.x;
    const int m0 = blockIdx.y * 64, n0 = blockIdx.x * 64;
    const int lane = tid & 63;
    const int wv = tid >> 6;
    const int wm = wv >> 1, wn = wv & 1;
    const int l15 = lane & 15, lg = lane >> 4;
    const int srow = tid >> 2, sk8 = (tid & 3) * 8;
    f32x4 acc[2][2] = {};
    const int NS = (K + 31) >> 5;
    const __hip_bfloat16* arow = A + (size_t)(m0 + srow) * K;
    const bool bvalid = (n0 + srow) < Nr;
    const __hip_bfloat16* brow = Bt + (size_t)(n0 + srow) * K;

    for (int s = 0; s < NS; s++) {
        const int gk = (s << 5) + sk8;
        if (s) __syncthreads();
        stage_row8(arow, true, K, gk, &As[srow][sk8]);
        stage_row8(brow, bvalid, K, gk, &Bs[srow][sk8]);
        __syncthreads();
        bf16x8 af0 = *(const bf16x8*)&As[wm * 32 + l15][lg * 8];
        bf16x8 af1 = *(const bf16x8*)&As[wm * 32 + 16 + l15][lg * 8];
        bf16x8 bf0 = *(const bf16x8*)&Bs[wn * 32 + l15][lg * 8];
        bf16x8 bf1 = *(const bf16x8*)&Bs[wn * 32 + 16 + l15][lg * 8];
        acc[0][0] = __builtin_amdgcn_mfma_f32_16x16x32_bf16(af0, bf0, acc[0][0], 0, 0, 0);
        acc[0][1] = __builtin_amdgcn_mfma_f32_16x16x32_bf16(af0, bf1, acc[0][1], 0, 0, 0);
        acc[1][0] = __builtin_amdgcn_mfma_f32_16x16x32_bf16(af1, bf0, acc[1][0], 0, 0, 0);
        acc[1][1] = __builtin_amdgcn_mfma_f32_16x16x32_bf16(af1, bf1, acc[1][1], 0, 0, 0);
    }

    #pragma unroll
    for (int fc = 0; fc < 2; fc++) {
        int col = n0 + wn * 32 + fc * 16 + l15;
        if (col >= Ns) continue;
        float bs = (col < Nr) ? bias[col] : 0.f;
        #pragma unroll
        for (int fr = 0; fr < 2; fr++) {
            int rbase = m0 + wm * 32 + fr * 16 + lg * 4;
            #pragma unroll
            for (int r = 0; r < 4; r++) {
                float v = acc[fr][fc][r] + bs;
                if (RELU) v = fmaxf(v, 0.f);
                Cb[(size_t)(rbase + r) * Ns + col] = __float2bfloat16(v);
            }
        }
    }
}

// ---------------- DIRECT-OPERAND GEMM + residual + LayerNorm (N = 300, no LDS) ----------
template <int NSTEP, int KSTR, int ASTR>
__global__ __launch_bounds__(256) void gemm_ln_direct(const __hip_bfloat16* __restrict__ A,
                                                      const __hip_bfloat16* __restrict__ Bt,
                                                      const float* __restrict__ bias,
                                                      const __hip_bfloat16* __restrict__ Res,
                                                      const float* __restrict__ g,
                                                      const float* __restrict__ beta,
                                                      __hip_bfloat16* __restrict__ Y) {
    const int tid = threadIdx.x;
    const int wv = tid >> 6;
    const int lane = tid & 63;
    const int l15 = lane & 15, lg = lane >> 4;
    const int m0 = blockIdx.x * 64 + wv * 16;

    f32x4 acc[19];
    #pragma unroll
    for (int fc = 0; fc < 19; fc++) acc[fc] = (f32x4){0.f, 0.f, 0.f, 0.f};

    #pragma unroll
    for (int ks = 0; ks < NSTEP; ks++) {
        const int kb = ks * 32 + lg * 8;
        bf16x8 af = *(const bf16x8*)(A + (size_t)(m0 + l15) * ASTR + kb);
        #pragma unroll
        for (int fc = 0; fc < 19; fc++) {
            bf16x8 bf = *(const bf16x8*)(Bt + (size_t)(fc * 16 + l15) * KSTR + kb);
            acc[fc] = __builtin_amdgcn_mfma_f32_16x16x32_bf16(af, bf, acc[fc], 0, 0, 0);
        }
    }

    float rs[4] = {0.f, 0.f, 0.f, 0.f};
    #pragma unroll
    for (int fc = 0; fc < 19; fc++) {
        int col = fc * 16 + l15;
        bool valid = col < EMB;
        float bs = valid ? bias[col] : 0.f;
        #pragma unroll
        for (int r = 0; r < 4; r++) {
            float v = 0.f;
            if (valid) v = acc[fc][r] + bs + bf2f(Res[(size_t)(m0 + lg * 4 + r) * EMB + col]);
            acc[fc][r] = v;
            rs[r] += v;
        }
    }
    #pragma unroll
    for (int r = 0; r < 4; r++)
        #pragma unroll
        for (int off = 1; off < 16; off <<= 1)
            rs[r] += __shfl_xor(rs[r], off);
    float mean[4], invv[4];
    #pragma unroll
    for (int r = 0; r < 4; r++) mean[r] = rs[r] * (1.f / EMB);

    float rq[4] = {0.f, 0.f, 0.f, 0.f};
    #pragma unroll
    for (int fc = 0; fc < 19; fc++) {
        int col = fc * 16 + l15;
        if (col < EMB) {
            #pragma unroll
            for (int r = 0; r < 4; r++) {
                float d = acc[fc][r] - mean[r];
                rq[r] += d * d;
            }
        }
    }
    #pragma unroll
    for (int r = 0; r < 4; r++) {
        #pragma unroll
        for (int off = 1; off < 16; off <<= 1)
            rq[r] += __shfl_xor(rq[r], off);
        float stdv = sqrtf(rq[r] * (1.f / (EMB - 1)));
        invv[r] = 1.f / (stdv + 1e-6f);
    }
    #pragma unroll
    for (int fc = 0; fc < 19; fc++) {
        int col = fc * 16 + l15;
        if (col >= EMB) continue;
        float gv = g[col], bv = beta[col];
        #pragma unroll
        for (int r = 0; r < 4; r++) {
            float y = gv * (acc[fc][r] - mean[r]) * invv[r] + bv;
            Y[(size_t)(m0 + lg * 4 + r) * EMB + col] = __float2bfloat16(y);
        }
    }
}

// ---------------- RBF accumulate: add 21 kernel responses of cv into ks[] ----------------
__device__ __forceinline__ void rbf_acc(float cv, float* ks) {
    float d0 = cv - 1.0f;
    ks[0] += __expf(d0 * d0 * -500000.0f);
    #pragma unroll
    for (int g = 0; g < 4; g++) {
        float mu_a = 0.95f - 0.5f * g;
        float dc = cv - mu_a;
        float t = __expf(dc * dc * -50.0f);
        float r = __expf(fmaf(-10.0f, dc, -0.5f));
        #pragma unroll
        for (int j = 0; j < 5; j++) {
            ks[1 + 5 * g + j] += t;
            t *= r;
            r *= 0.36787944117144233f;   // e^-1
        }
    }
}

// ---------------- FUSED cos GEMM + kernel pooling (atomic fp32 partials) ----------------
// Per block: 64x64 cos tile (batch b, d-cols n0..n0+63) via MFMA; epilogue computes the
// 21 RBF partial sums per q-row over this block's cols and atomicAdds into lpraw[b][q][k].
__global__ __launch_bounds__(256) void cos_pool_mfma(const __hip_bfloat16* __restrict__ Qn,
                                                     const __hip_bfloat16* __restrict__ Dn,
                                                     const float* __restrict__ mask_d,
                                                     float* __restrict__ lpraw) {
    __shared__ __align__(16) __hip_bfloat16 As[64][40];
    __shared__ __align__(16) __hip_bfloat16 Bs[64][40];
    const int b = blockIdx.y;
    const int n0 = blockIdx.x * 64;
    const int tid = threadIdx.x;
    const int lane = tid & 63;
    const int wv = tid >> 6;
    const int wm = wv >> 1, wn = wv & 1;
    const int l15 = lane & 15, lg = lane >> 4;
    const int srow = tid >> 2, sk8 = (tid & 3) * 8;
    f32x4 acc[2][2] = {};
    const int NS = (EMB + 31) >> 5;   // 10
    const __hip_bfloat16* arow = Qn + ((size_t)b * LQ + srow) * EMB;
    const __hip_bfloat16* brow = Dn + ((size_t)b * LD + n0 + srow) * EMB;

    for (int s = 0; s < NS; s++) {
        const int gk = (s << 5) + sk8;
        if (s) __syncthreads();
        stage_row8(arow, true, EMB, gk, &As[srow][sk8]);
        stage_row8(brow, true, EMB, gk, &Bs[srow][sk8]);
        __syncthreads();
        bf16x8 af0 = *(const bf16x8*)&As[wm * 32 + l15][lg * 8];
        bf16x8 af1 = *(const bf16x8*)&As[wm * 32 + 16 + l15][lg * 8];
        bf16x8 bf0 = *(const bf16x8*)&Bs[wn * 32 + l15][lg * 8];
        bf16x8 bf1 = *(const bf16x8*)&Bs[wn * 32 + 16 + l15][lg * 8];
        acc[0][0] = __builtin_amdgcn_mfma_f32_16x16x32_bf16(af0, bf0, acc[0][0], 0, 0, 0);
        acc[0][1] = __builtin_amdgcn_mfma_f32_16x16x32_bf16(af0, bf1, acc[0][1], 0, 0, 0);
        acc[1][0] = __builtin_amdgcn_mfma_f32_16x16x32_bf16(af1, bf0, acc[1][0], 0, 0, 0);
        acc[1][1] = __builtin_amdgcn_mfma_f32_16x16x32_bf16(af1, bf1, acc[1][1], 0, 0, 0);
    }

    // masks for this lane's two columns
    const float* md = mask_d + b * LD;
    float mc0 = md[n0 + wn * 32 + l15];
    float mc1 = md[n0 + wn * 32 + 16 + l15];

    #pragma unroll
    for (int fr = 0; fr < 2; fr++) {
        #pragma unroll
        for (int r = 0; r < 4; r++) {
            int qrow = wm * 32 + fr * 16 + lg * 4 + r;
            float ks[NK];
            #pragma unroll
            for (int k = 0; k < NK; k++) ks[k] = 0.f;
            if (mc0 != 0.f) rbf_acc(acc[fr][0][r], ks);
            if (mc1 != 0.f) rbf_acc(acc[fr][1][r], ks);
            #pragma unroll
            for (int k = 0; k < NK; k++) {
                #pragma unroll
                for (int off = 1; off < 16; off <<= 1)
                    ks[k] += __shfl_xor(ks[k], off);
            }
            if (l15 == 0) {
                float* dst = lpraw + ((size_t)b * LQ + qrow) * NK;
                #pragma unroll
                for (int k = 0; k < NK; k++) atomicAdd(&dst[k], ks[k]);
            }
        }
    }
}

// ---------------- attention body (templated), smem carved by caller ----------------
template <int T, int RPB, int KS>
__device__ __forceinline__ void attn_body(const __hip_bfloat16* __restrict__ cseg,
                                          const float* __restrict__ mask,
                                          __hip_bfloat16* __restrict__ oseg,
                                          int bh, int rb, char* smem) {
    constexpr int BLK = 512;
    float4* Ks = (float4*)smem;
    float4* Vs = Ks + T;
    float* part = (float*)(Vs + T);
    float* nmask_s = part + RPB * 5 * (KS - 1);
    const int b = bh / NH, h = bh % NH;
    const int tid = threadIdx.x;
    const __hip_bfloat16* base = cseg + (size_t)b * T * 96;

    if (tid == 0) *nmask_s = 0.f;
    __syncthreads();
    float lnm = 0.f;
    for (int j = tid; j < T; j += BLK) {
        float m = mask[b * T + j];
        float4 kv = bf4_to_f4(base + (size_t)j * 96 + ATTD + h * 4);
        float4 vv = bf4_to_f4(base + (size_t)j * 96 + 2 * ATTD + h * 4);
        kv.x *= m; kv.y *= m; kv.z *= m; kv.w *= m;
        vv.x *= m; vv.y *= m; vv.z *= m; vv.w *= m;
        Ks[j] = kv;
        Vs[j] = vv;
        lnm += 1.f - m;
    }
    lnm = wave_sum(lnm);
    if ((tid & 63) == 0 && lnm != 0.f) atomicAdd(nmask_s, lnm);
    __syncthreads();

    const int r = rb * RPB + (tid % RPB);
    const int ks = tid / RPB;
    const float inv_scale = 0.16439898730535729f;  // 1/sqrt(37)
    float4 qv = bf4_to_f4(base + (size_t)r * 96 + h * 4);
    qv.x *= inv_scale; qv.y *= inv_scale; qv.z *= inv_scale; qv.w *= inv_scale;

    float Sall = 0.f, ox = 0.f, oy = 0.f, oz = 0.f, ow = 0.f;
    constexpr int KC = T / KS;
    const int k0 = ks * KC;
    #pragma unroll 4
    for (int k = k0; k < k0 + KC; k++) {
        float4 kv = Ks[k];
        float4 vv = Vs[k];
        float s = fmaf(qv.x, kv.x, fmaf(qv.y, kv.y, fmaf(qv.z, kv.z, qv.w * kv.w)));
        float e = __expf(s);
        Sall += e;
        ox = fmaf(e, vv.x, ox);
        oy = fmaf(e, vv.y, oy);
        oz = fmaf(e, vv.z, oz);
        ow = fmaf(e, vv.w, ow);
    }
    if (ks > 0) {
        float* p = &part[((ks - 1) * RPB + (tid % RPB)) * 5];
        p[0] = Sall; p[1] = ox; p[2] = oy; p[3] = oz; p[4] = ow;
    }
    __syncthreads();
    if (ks == 0) {
        #pragma unroll
        for (int s2 = 0; s2 < KS - 1; s2++) {
            const float* p = &part[(s2 * RPB + r - rb * RPB) * 5];
            Sall += p[0]; ox += p[1]; oy += p[2]; oz += p[3]; ow += p[4];
        }
        float Sm = Sall - *nmask_s;
        float inv = 1.f / (Sm + 1e-13f * Sall);
        __hip_bfloat16* op = oseg + (size_t)(b * T + r) * ATTD + h * 4;
        op[0] = __float2bfloat16(ox * inv);
        op[1] = __float2bfloat16(oy * inv);
        op[2] = __float2bfloat16(oz * inv);
        op[3] = __float2bfloat16(ow * inv);
    }
}

// ---------------- merged q+d attention: blocks [0,256) = q, [256,1280) = d ----------------
__global__ __launch_bounds__(512) void attn_both(const __hip_bfloat16* __restrict__ cbf,
                                                 const float* __restrict__ mask_q,
                                                 const float* __restrict__ mask_d,
                                                 __hip_bfloat16* __restrict__ o32) {
    __shared__ __align__(16) char smem[24576];
    int blk = blockIdx.x;
    if (blk < BATCH * NH) {
        attn_body<LQ, 64, 8>(cbf, mask_q, o32, blk, 0, smem);
    } else {
        int bid = blk - BATCH * NH;
        attn_body<LD, 128, 4>(cbf + (size_t)MQ * 96, mask_d, o32 + (size_t)MQ * ATTD,
                              bid >> 2, bid & 3, smem);
    }
}

// ---------------- mix + L2 normalize (bf16 in/out), uint2-vectorized ----------------
// One wave per token; 75 chunks of 4 bf16 per row (300 elems); chunk = lane, 64+lane(<11).
__global__ __launch_bounds__(256) void mixnorm_bf(const __hip_bfloat16* __restrict__ x,
                                                  const __hip_bfloat16* __restrict__ xc,
                                                  const float* __restrict__ mask,
                                                  const float* __restrict__ mixer,
                                                  __hip_bfloat16* __restrict__ out) {
    int wid = (blockIdx.x * 256 + threadIdx.x) >> 6;
    int lane = threadIdx.x & 63;
    float mixv = mixer[0];
    float mval = mask[wid];
    const __hip_bfloat16* xr = x + (size_t)wid * EMB;
    const __hip_bfloat16* xcr = xc + (size_t)wid * EMB;
    const bool hasB = lane < 11;
    float vA[4], vB[4];
    float s2 = 0.f;
    {
        float4 xa = bf4_to_f4(xr + lane * 4);
        float4 xca = bf4_to_f4(xcr + lane * 4);
        vA[0] = (mixv * xa.x + (1.f - mixv) * xca.x) * mval;
        vA[1] = (mixv * xa.y + (1.f - mixv) * xca.y) * mval;
        vA[2] = (mixv * xa.z + (1.f - mixv) * xca.z) * mval;
        vA[3] = (mixv * xa.w + (1.f - mixv) * xca.w) * mval;
        s2 += vA[0] * vA[0] + vA[1] * vA[1] + vA[2] * vA[2] + vA[3] * vA[3];
    }
    if (hasB) {
        int c = 64 + lane;
        float4 xa = bf4_to_f4(xr + c * 4);
        float4 xca = bf4_to_f4(xcr + c * 4);
        vB[0] = (mixv * xa.x + (1.f - mixv) * xca.x) * mval;
        vB[1] = (mixv * xa.y + (1.f - mixv) * xca.y) * mval;
        vB[2] = (mixv * xa.z + (1.f - mixv) * xca.z) * mval;
        vB[3] = (mixv * xa.w + (1.f - mixv) * xca.w) * mval;
        s2 += vB[0] * vB[0] + vB[1] * vB[1] + vB[2] * vB[2] + vB[3] * vB[3];
    }
    s2 = wave_sum(s2);
    float inv = 1.f / (sqrtf(s2) + 1e-13f);
    __hip_bfloat16* o = out + (size_t)wid * EMB;
    {
        uint2 u;
        u.x = (unsigned)f2bfu(vA[0] * inv) | ((unsigned)f2bfu(vA[1] * inv) << 16);
        u.y = (unsigned)f2bfu(vA[2] * inv) | ((unsigned)f2bfu(vA[3] * inv) << 16);
        *(uint2*)(o + lane * 4) = u;
    }
    if (hasB) {
        int c = 64 + lane;
        uint2 u;
        u.x = (unsigned)f2bfu(vB[0] * inv) | ((unsigned)f2bfu(vB[1] * inv) << 16);
        u.y = (unsigned)f2bfu(vB[2] * inv) | ((unsigned)f2bfu(vB[3] * inv) << 16);
        *(uint2*)(o + c * 4) = u;
    }
}

// ---------------- final: out[b] = sum_k dense_w[k]*ns* sum_qi log2(clip(lpraw))*mq -------
__global__ void final_kernel(const float* __restrict__ lpraw, const float* __restrict__ mask_q,
                             const float* __restrict__ nn_scaler, const float* __restrict__ dense_w,
                             float* __restrict__ out) {
    int b = blockIdx.x;
    int t = threadIdx.x;  // 64 threads
    float s = 0.f;
    if (t < NK) {
        for (int qi = 0; qi < LQ; qi++) {
            float pkq = lpraw[((size_t)b * LQ + qi) * NK + t];
            s += log2f(fmaxf(pkq, 1e-10f)) * mask_q[b * LQ + qi];
        }
        s *= nn_scaler[0] * dense_w[t];
    }
    s = wave_sum(s);
    if (t == 0) out[b] = s;
}

extern "C" void kernel_launch(void* const* d_in, const int* in_sizes, int n_in,
                              void* d_out, int out_size, void* d_ws, size_t ws_size,
                              hipStream_t stream) {
    (void)in_sizes; (void)n_in; (void)out_size; (void)ws_size;
    const float* q_embed  = (const float*)d_in[0];
    const float* d_embed  = (const float*)d_in[1];
    const float* mask_q   = (const float*)d_in[2];
    const float* mask_d   = (const float*)d_in[3];
    const float* mixer    = (const float*)d_in[4];
    const float* nn_scaler= (const float*)d_in[5];
    const float* ff_w1    = (const float*)d_in[6];
    const float* ff_b1    = (const float*)d_in[7];
    const float* ff_w2    = (const float*)d_in[8];
    const float* ff_b2    = (const float*)d_in[9];
    const float* ln1_g    = (const float*)d_in[10];
    const float* ln1_b    = (const float*)d_in[11];
    const float* att_w    = (const float*)d_in[12];
    const float* att_b    = (const float*)d_in[13];
    const float* out_w    = (const float*)d_in[14];
    const float* out_b    = (const float*)d_in[15];
    const float* ln2_g    = (const float*)d_in[16];
    const float* ln2_b    = (const float*)d_in[17];
    const float* dense_w  = (const float*)d_in[18];
    float* out = (float*)d_out;

    // ---------------- workspace layout ----------------
    float* ws    = (float*)d_ws;
    float* lpraw = ws;                        // 32*64*21 = 43,008 fp32 (atomic partials)
    float* mall  = lpraw + 43008;             // 18,432
    __hip_bfloat16* xbf   = (__hip_bfloat16*)(mall + MALL);   // MALL*EMB (masked emb, persists)
    __hip_bfloat16* xcbf  = xbf  + (size_t)MALL * EMB;        // layer-0 output
    __hip_bfloat16* xc2bf = xcbf + (size_t)MALL * EMB;        // layer-1 output
    __hip_bfloat16* hbf   = xc2bf + (size_t)MALL * EMB;       // LN1 out; later qdn
    __hip_bfloat16* t1bf  = hbf  + (size_t)MALL * EMB;        // MALL*128 (stride-128, zero-pad)
    __hip_bfloat16* cbf   = t1bf + (size_t)MALL * 128;        // MALL*96
    __hip_bfloat16* o32bf = cbf  + (size_t)MALL * 96;         // MALL*ATTD
    __hip_bfloat16* w1t   = o32bf + (size_t)MALL * ATTD;      // 2*100*300
    __hip_bfloat16* w2t   = w1t + 2 * FFH * EMB;              // 2*320*128 (padded)
    __hip_bfloat16* awt   = w2t + 2 * 320 * 128;              // 2*96*300
    __hip_bfloat16* owt   = awt + 2 * 96 * EMB;               // 2*320*32 (padded)

    // 0. weights (bf16, transposed, padded) + lpraw zero, one kernel
    convert_all<<<(263008 + 255) / 256, 256, 0, stream>>>(ff_w1, ff_w2, att_w, out_w,
                                                          w1t, w2t, awt, owt, lpraw);
    // 1. masked inputs (bf16) + concat masks in one kernel
    maskmul_all<<<(MALL * EMB + 255) / 256, 256, 0, stream>>>(q_embed, d_embed, mask_q, mask_d,
                                                              xbf, mall);

    // 2. merged encoder, bf16 stream
    const __hip_bfloat16* xcur = xbf;
    for (int l = 0; l < 2; l++) {
        __hip_bfloat16* xout = (l == 0) ? xcbf : xc2bf;
        // FF1: relu(x @ w1 + b1) -> t1bf (stride 128, cols 100..127 zeroed)
        gemm_mfma<true><<<dim3(2, MALL / 64), 256, 0, stream>>>(
            xcur, w1t + (size_t)l * FFH * EMB, ff_b1 + l * FFH, t1bf, MALL, FFH, 128, EMB);
        // FF2 + residual(x) + LN1 -> hbf   (direct, K=128 padded)
        gemm_ln_direct<4, 128, 128><<<MALL / 64, 256, 0, stream>>>(
            t1bf, w2t + (size_t)l * 320 * 128, ff_b2 + l * EMB, xcur,
            ln1_g + l * EMB, ln1_b + l * EMB, hbf);
        // ATT: h @ att_w + att_b -> cbf
        gemm_mfma<false><<<dim3(2, MALL / 64), 256, 0, stream>>>(
            hbf, awt + (size_t)l * 96 * EMB, att_b + l * 96, cbf, MALL, 96, 96, EMB);
        // attention (q + d merged) -> o32bf
        attn_both<<<BATCH * NH + BATCH * NH * (LD / 128), 512, 0, stream>>>(
            cbf, mask_q, mask_d, o32bf);
        // OUT + residual(h) + LN2 -> xout  (direct, K=32)
        gemm_ln_direct<1, 32, 32><<<MALL / 64, 256, 0, stream>>>(
            o32bf, owt + (size_t)l * 320 * 32, out_b + l * EMB, hbf,
            ln2_g + l * EMB, ln2_b + l * EMB, xout);
        xcur = xout;
    }

    // 3. mix + normalize -> hbf (free after encoder)
    mixnorm_bf<<<MALL / 4, 256, 0, stream>>>(xbf, xc2bf, mall, mixer, hbf);

    // 4. fused cosine + kernel pooling -> lpraw (atomic partials)
    cos_pool_mfma<<<dim3(LD / 64, BATCH), 256, 0, stream>>>(
        hbf, hbf + (size_t)MQ * EMB, mask_d, lpraw);

    // 5. final projection (log/mask/dense folded in)
    final_kernel<<<BATCH, 64, 0, stream>>>(lpraw, mask_q, nn_scaler, dense_w, out);
}

// Round 15
// 250.595 us; speedup vs baseline: 1.1645x; 1.1645x over previous
//
#include <hip/hip_runtime.h>
#include <hip/hip_bf16.h>

// Problem constants
#define BATCH 32
#define LQ 64
#define LD 512
#define EMB 300
#define FFH 100
#define ATTD 32
#define NH 8
#define NK 21
#define MQ (BATCH * LQ)          // 2048 query tokens
#define MD (BATCH * LD)          // 16384 doc tokens
#define MALL (MQ + MD)           // 18432 merged tokens
#define STR 320                  // padded row stride for EMB-width tensors (8*40)

typedef __attribute__((ext_vector_type(8))) short bf16x8;
typedef __attribute__((ext_vector_type(4))) float f32x4;

__device__ __forceinline__ float wave_sum(float v) {
    #pragma unroll
    for (int off = 32; off > 0; off >>= 1) v += __shfl_xor(v, off);
    return v;
}

__device__ __forceinline__ float bf2f(__hip_bfloat16 h) { return __bfloat162float(h); }

// 4 consecutive bf16 -> float4 (8B-aligned source)
__device__ __forceinline__ float4 bf4_to_f4(const __hip_bfloat16* p) {
    uint2 u = *(const uint2*)p;
    float4 f;
    f.x = __uint_as_float((u.x & 0xffffu) << 16);
    f.y = __uint_as_float(u.x & 0xffff0000u);
    f.z = __uint_as_float((u.y & 0xffffu) << 16);
    f.w = __uint_as_float(u.y & 0xffff0000u);
    return f;
}

__device__ __forceinline__ unsigned short f2bfu(float x) {
    __hip_bfloat16 h = __float2bfloat16(x);
    return *(unsigned short*)&h;
}

// ---------------- fused prep: masked embeddings (stride 320) + masks + weights ------------
// xbf[tok*320+c] = bf16(emb*mask); weights converted/transposed/zero-padded:
// w1t [l][112][320], w2t [l][304][128], awt [l][96][320], owt [l][304][32].
__global__ void prep_all(const float* __restrict__ qe, const float* __restrict__ de,
                         const float* __restrict__ mq, const float* __restrict__ md,
                         const float* __restrict__ w1, const float* __restrict__ w2,
                         const float* __restrict__ aw, const float* __restrict__ ow,
                         __hip_bfloat16* __restrict__ xbf, float* __restrict__ mall,
                         __hip_bfloat16* __restrict__ w1t, __hip_bfloat16* __restrict__ w2t,
                         __hip_bfloat16* __restrict__ awt, __hip_bfloat16* __restrict__ owt) {
    int i = blockIdx.x * blockDim.x + threadIdx.x;
    const int NM = MALL * EMB;                 // 5,529,600
    if (i < NM) {
        int tok = i / EMB, c = i % EMB;
        float m, v;
        if (tok < MQ) { m = mq[tok]; v = qe[i]; }
        else          { m = md[tok - MQ]; v = de[i - MQ * EMB]; }
        xbf[(size_t)tok * STR + c] = __float2bfloat16(v * m);
        if (c == 0) mall[tok] = m;
        return;
    }
    int j = i - NM;
    if (j < 2 * 112 * 320) {                               // w1t
        int l = j / (112 * 320), r = j % (112 * 320);
        int n = r / 320, k = r % 320;
        float v = (n < FFH && k < EMB) ? w1[(size_t)l * EMB * FFH + (size_t)k * FFH + n] : 0.f;
        w1t[j] = __float2bfloat16(v);
        return;
    }
    j -= 2 * 112 * 320;
    if (j < 2 * 304 * 128) {                               // w2t
        int l = j / (304 * 128), r = j % (304 * 128);
        int n = r / 128, k = r % 128;
        float v = (n < EMB && k < FFH) ? w2[(size_t)l * FFH * EMB + (size_t)k * EMB + n] : 0.f;
        w2t[j] = __float2bfloat16(v);
        return;
    }
    j -= 2 * 304 * 128;
    if (j < 2 * 96 * 320) {                                // awt
        int l = j / (96 * 320), r = j % (96 * 320);
        int n = r / 320, k = r % 320;
        float v = (k < EMB) ? aw[(size_t)l * EMB * 96 + (size_t)k * 96 + n] : 0.f;
        awt[j] = __float2bfloat16(v);
        return;
    }
    j -= 2 * 96 * 320;
    if (j < 2 * 304 * 32) {                                // owt
        int l = j / (304 * 32), r = j % (304 * 32);
        int n = r / 32, k = r % 32;
        float v = (n < EMB) ? ow[(size_t)l * ATTD * EMB + (size_t)k * EMB + n] : 0.f;
        owt[j] = __float2bfloat16(v);
    }
}

// ---------------- shared staging helper: 8 bf16 of one row ----------------
__device__ __forceinline__ void stage_row8(const __hip_bfloat16* __restrict__ src, bool rowvalid,
                                           int K, int gk, __hip_bfloat16* dst) {
    if (rowvalid && gk + 8 <= K) {
        const uint2* p = (const uint2*)(src + gk);
        uint2 a = p[0], b = p[1];
        *(uint2*)dst = a;
        *(uint2*)(dst + 4) = b;
    } else {
        #pragma unroll
        for (int j = 0; j < 8; j++)
            dst[j] = (rowvalid && gk + j < K) ? src[gk + j] : __float2bfloat16(0.f);
    }
}

// ---------------- FUSED ENCODER ROW KERNEL: FF1 -> FF2+LN1 -> ATT projection -------------
// Block = 64 rows, 256 thr = 4 waves; wave wv owns rows [wv*16, wv*16+16) completely.
// All MFMA operands loaded direct (global for X/weights, LDS for t1/h).
// D layout (m89-verified): col = lane&15, row = (lane>>4)*4 + reg.
__global__ __launch_bounds__(256) void enc_fused(const __hip_bfloat16* __restrict__ X,
                                                 const __hip_bfloat16* __restrict__ W1t,
                                                 const float* __restrict__ b1,
                                                 const __hip_bfloat16* __restrict__ W2t,
                                                 const float* __restrict__ b2,
                                                 const float* __restrict__ g1,
                                                 const float* __restrict__ bt1,
                                                 const __hip_bfloat16* __restrict__ AWt,
                                                 const float* __restrict__ ab,
                                                 __hip_bfloat16* __restrict__ Hout,
                                                 __hip_bfloat16* __restrict__ Cout) {
    __shared__ __align__(16) __hip_bfloat16 t1s[64][136];   // cols 0..127 used (100 real)
    __shared__ __align__(16) __hip_bfloat16 hs[64][328];    // cols 0..319 used (300 real)
    const int tid = threadIdx.x;
    const int wv = tid >> 6, lane = tid & 63;
    const int l15 = lane & 15, lg = lane >> 4;
    const int m0 = blockIdx.x * 64;
    const int rw = wv * 16;

    // zero pad regions (t1s cols 112-127, hs cols 304-319)
    {
        int rr = tid >> 2, cc = (tid & 3) * 4;
        *(uint2*)&t1s[rr][112 + cc] = (uint2){0u, 0u};
        *(uint2*)&hs[rr][304 + cc] = (uint2){0u, 0u};
    }

    // ---- Phase 1: t1 = relu(x @ w1 + b1) (cols 0..111; 100 real) ----
    {
        f32x4 a1[7];
        #pragma unroll
        for (int fc = 0; fc < 7; fc++) a1[fc] = (f32x4){0.f, 0.f, 0.f, 0.f};
        #pragma unroll
        for (int ks = 0; ks < 10; ks++) {
            const int kb = ks * 32 + lg * 8;
            bf16x8 af = *(const bf16x8*)(X + (size_t)(m0 + rw + l15) * STR + kb);
            #pragma unroll
            for (int fc = 0; fc < 7; fc++) {
                bf16x8 bf = *(const bf16x8*)(W1t + (size_t)(fc * 16 + l15) * STR + kb);
                a1[fc] = __builtin_amdgcn_mfma_f32_16x16x32_bf16(af, bf, a1[fc], 0, 0, 0);
            }
        }
        #pragma unroll
        for (int fc = 0; fc < 7; fc++) {
            int col = fc * 16 + l15;
            float bs = (col < FFH) ? b1[col] : 0.f;
            #pragma unroll
            for (int r = 0; r < 4; r++) {
                float v = fmaxf(a1[fc][r] + bs, 0.f);
                t1s[rw + lg * 4 + r][col] = __float2bfloat16(v);
            }
        }
    }
    __syncthreads();

    // ---- Phase 2: h = LN(t1 @ w2 + b2 + x) ----
    {
        f32x4 a2[19];
        #pragma unroll
        for (int fc = 0; fc < 19; fc++) a2[fc] = (f32x4){0.f, 0.f, 0.f, 0.f};
        #pragma unroll
        for (int ks = 0; ks < 4; ks++) {
            const int kb = ks * 32 + lg * 8;
            bf16x8 af = *(const bf16x8*)&t1s[rw + l15][kb];
            #pragma unroll
            for (int fc = 0; fc < 19; fc++) {
                bf16x8 bf = *(const bf16x8*)(W2t + (size_t)(fc * 16 + l15) * 128 + kb);
                a2[fc] = __builtin_amdgcn_mfma_f32_16x16x32_bf16(af, bf, a2[fc], 0, 0, 0);
            }
        }
        float rs[4] = {0.f, 0.f, 0.f, 0.f};
        #pragma unroll
        for (int fc = 0; fc < 19; fc++) {
            int col = fc * 16 + l15;
            bool valid = col < EMB;
            float bs = valid ? b2[col] : 0.f;
            #pragma unroll
            for (int r = 0; r < 4; r++) {
                float v = 0.f;
                if (valid) v = a2[fc][r] + bs + bf2f(X[(size_t)(m0 + rw + lg * 4 + r) * STR + col]);
                a2[fc][r] = v;
                rs[r] += v;
            }
        }
        #pragma unroll
        for (int r = 0; r < 4; r++)
            #pragma unroll
            for (int off = 1; off < 16; off <<= 1)
                rs[r] += __shfl_xor(rs[r], off);
        float mean[4], invv[4];
        #pragma unroll
        for (int r = 0; r < 4; r++) mean[r] = rs[r] * (1.f / EMB);
        float rq[4] = {0.f, 0.f, 0.f, 0.f};
        #pragma unroll
        for (int fc = 0; fc < 19; fc++) {
            int col = fc * 16 + l15;
            if (col < EMB) {
                #pragma unroll
                for (int r = 0; r < 4; r++) {
                    float d = a2[fc][r] - mean[r];
                    rq[r] += d * d;
                }
            }
        }
        #pragma unroll
        for (int r = 0; r < 4; r++) {
            #pragma unroll
            for (int off = 1; off < 16; off <<= 1)
                rq[r] += __shfl_xor(rq[r], off);
            float stdv = sqrtf(rq[r] * (1.f / (EMB - 1)));
            invv[r] = 1.f / (stdv + 1e-6f);
        }
        #pragma unroll
        for (int fc = 0; fc < 19; fc++) {
            int col = fc * 16 + l15;
            if (col < EMB) {
                float gv = g1[col], bv = bt1[col];
                #pragma unroll
                for (int r = 0; r < 4; r++) {
                    int row = rw + lg * 4 + r;
                    float y = gv * (a2[fc][r] - mean[r]) * invv[r] + bv;
                    __hip_bfloat16 yb = __float2bfloat16(y);
                    hs[row][col] = yb;
                    Hout[(size_t)(m0 + row) * STR + col] = yb;
                }
            } else {
                #pragma unroll
                for (int r = 0; r < 4; r++) hs[rw + lg * 4 + r][col] = __float2bfloat16(0.f);
            }
        }
    }
    __syncthreads();

    // ---- Phase 3: c = h @ aw + ab (96 cols) ----
    {
        f32x4 a3[6];
        #pragma unroll
        for (int fc = 0; fc < 6; fc++) a3[fc] = (f32x4){0.f, 0.f, 0.f, 0.f};
        #pragma unroll
        for (int ks = 0; ks < 10; ks++) {
            const int kb = ks * 32 + lg * 8;
            bf16x8 af = *(const bf16x8*)&hs[rw + l15][kb];
            #pragma unroll
            for (int fc = 0; fc < 6; fc++) {
                bf16x8 bf = *(const bf16x8*)(AWt + (size_t)(fc * 16 + l15) * STR + kb);
                a3[fc] = __builtin_amdgcn_mfma_f32_16x16x32_bf16(af, bf, a3[fc], 0, 0, 0);
            }
        }
        #pragma unroll
        for (int fc = 0; fc < 6; fc++) {
            int col = fc * 16 + l15;
            float bs = ab[col];
            #pragma unroll
            for (int r = 0; r < 4; r++)
                Cout[(size_t)(m0 + rw + lg * 4 + r) * 96 + col] =
                    __float2bfloat16(a3[fc][r] + bs);
        }
    }
}

// ---------------- DIRECT-OPERAND GEMM + residual + LayerNorm (OUT projection) ----------
// A [M][ASTR] (K real = NSTEP*32 range), Bt [304][KSTR] zero-padded, Res/Y stride RSTR.
template <int NSTEP, int KSTR, int ASTR, int RSTR>
__global__ __launch_bounds__(256) void gemm_ln_direct(const __hip_bfloat16* __restrict__ A,
                                                      const __hip_bfloat16* __restrict__ Bt,
                                                      const float* __restrict__ bias,
                                                      const __hip_bfloat16* __restrict__ Res,
                                                      const float* __restrict__ g,
                                                      const float* __restrict__ beta,
                                                      __hip_bfloat16* __restrict__ Y) {
    const int tid = threadIdx.x;
    const int wv = tid >> 6;
    const int lane = tid & 63;
    const int l15 = lane & 15, lg = lane >> 4;
    const int m0 = blockIdx.x * 64 + wv * 16;

    f32x4 acc[19];
    #pragma unroll
    for (int fc = 0; fc < 19; fc++) acc[fc] = (f32x4){0.f, 0.f, 0.f, 0.f};

    #pragma unroll
    for (int ks = 0; ks < NSTEP; ks++) {
        const int kb = ks * 32 + lg * 8;
        bf16x8 af = *(const bf16x8*)(A + (size_t)(m0 + l15) * ASTR + kb);
        #pragma unroll
        for (int fc = 0; fc < 19; fc++) {
            bf16x8 bf = *(const bf16x8*)(Bt + (size_t)(fc * 16 + l15) * KSTR + kb);
            acc[fc] = __builtin_amdgcn_mfma_f32_16x16x32_bf16(af, bf, acc[fc], 0, 0, 0);
        }
    }

    float rs[4] = {0.f, 0.f, 0.f, 0.f};
    #pragma unroll
    for (int fc = 0; fc < 19; fc++) {
        int col = fc * 16 + l15;
        bool valid = col < EMB;
        float bs = valid ? bias[col] : 0.f;
        #pragma unroll
        for (int r = 0; r < 4; r++) {
            float v = 0.f;
            if (valid) v = acc[fc][r] + bs + bf2f(Res[(size_t)(m0 + lg * 4 + r) * RSTR + col]);
            acc[fc][r] = v;
            rs[r] += v;
        }
    }
    #pragma unroll
    for (int r = 0; r < 4; r++)
        #pragma unroll
        for (int off = 1; off < 16; off <<= 1)
            rs[r] += __shfl_xor(rs[r], off);
    float mean[4], invv[4];
    #pragma unroll
    for (int r = 0; r < 4; r++) mean[r] = rs[r] * (1.f / EMB);

    float rq[4] = {0.f, 0.f, 0.f, 0.f};
    #pragma unroll
    for (int fc = 0; fc < 19; fc++) {
        int col = fc * 16 + l15;
        if (col < EMB) {
            #pragma unroll
            for (int r = 0; r < 4; r++) {
                float d = acc[fc][r] - mean[r];
                rq[r] += d * d;
            }
        }
    }
    #pragma unroll
    for (int r = 0; r < 4; r++) {
        #pragma unroll
        for (int off = 1; off < 16; off <<= 1)
            rq[r] += __shfl_xor(rq[r], off);
        float stdv = sqrtf(rq[r] * (1.f / (EMB - 1)));
        invv[r] = 1.f / (stdv + 1e-6f);
    }
    #pragma unroll
    for (int fc = 0; fc < 19; fc++) {
        int col = fc * 16 + l15;
        if (col >= EMB) continue;
        float gv = g[col], bv = beta[col];
        #pragma unroll
        for (int r = 0; r < 4; r++) {
            float y = gv * (acc[fc][r] - mean[r]) * invv[r] + bv;
            Y[(size_t)(m0 + lg * 4 + r) * RSTR + col] = __float2bfloat16(y);
        }
    }
}

// ---------------- batched MFMA cos GEMM (row stride 320): Cos[b] = Qn[b] @ Dn[b]^T -------
__global__ __launch_bounds__(256) void cos_mfma(const __hip_bfloat16* __restrict__ Qn,
                                                const __hip_bfloat16* __restrict__ Dn,
                                                float* __restrict__ Cos) {
    __shared__ __align__(16) __hip_bfloat16 As[64][40];
    __shared__ __align__(16) __hip_bfloat16 Bs[64][40];
    const int b = blockIdx.y;
    const int n0 = blockIdx.x * 64;
    const int tid = threadIdx.x;
    const int lane = tid & 63;
    const int wv = tid >> 6;
    const int wm = wv >> 1, wn = wv & 1;
    const int l15 = lane & 15, lg = lane >> 4;
    const int srow = tid >> 2, sk8 = (tid & 3) * 8;
    f32x4 acc[2][2] = {};
    const int NS = (EMB + 31) >> 5;   // 10
    const __hip_bfloat16* arow = Qn + (size_t)(b * LQ + srow) * STR;
    const __hip_bfloat16* brow = Dn + (size_t)(b * LD + n0 + srow) * STR;

    for (int s = 0; s < NS; s++) {
        const int gk = (s << 5) + sk8;
        if (s) __syncthreads();
        stage_row8(arow, true, EMB, gk, &As[srow][sk8]);
        stage_row8(brow, true, EMB, gk, &Bs[srow][sk8]);
        __syncthreads();
        bf16x8 af0 = *(const bf16x8*)&As[wm * 32 + l15][lg * 8];
        bf16x8 af1 = *(const bf16x8*)&As[wm * 32 + 16 + l15][lg * 8];
        bf16x8 bf0 = *(const bf16x8*)&Bs[wn * 32 + l15][lg * 8];
        bf16x8 bf1 = *(const bf16x8*)&Bs[wn * 32 + 16 + l15][lg * 8];
        acc[0][0] = __builtin_amdgcn_mfma_f32_16x16x32_bf16(af0, bf0, acc[0][0], 0, 0, 0);
        acc[0][1] = __builtin_amdgcn_mfma_f32_16x16x32_bf16(af0, bf1, acc[0][1], 0, 0, 0);
        acc[1][0] = __builtin_amdgcn_mfma_f32_16x16x32_bf16(af1, bf0, acc[1][0], 0, 0, 0);
        acc[1][1] = __builtin_amdgcn_mfma_f32_16x16x32_bf16(af1, bf1, acc[1][1], 0, 0, 0);
    }

    float* cb = Cos + (size_t)b * LQ * LD;
    #pragma unroll
    for (int fc = 0; fc < 2; fc++) {
        int col = n0 + wn * 32 + fc * 16 + l15;
        #pragma unroll
        for (int fr = 0; fr < 2; fr++) {
            int rbase = wm * 32 + fr * 16 + lg * 4;
            #pragma unroll
            for (int r = 0; r < 4; r++) {
                cb[(size_t)(rbase + r) * LD + col] = acc[fr][fc][r];
            }
        }
    }
}

// ---------------- attention body (templated), smem carved by caller ----------------
template <int T, int RPB, int KS>
__device__ __forceinline__ void attn_body(const __hip_bfloat16* __restrict__ cseg,
                                          const float* __restrict__ mask,
                                          __hip_bfloat16* __restrict__ oseg,
                                          int bh, int rb, char* smem) {
    constexpr int BLK = 512;
    float4* Ks = (float4*)smem;
    float4* Vs = Ks + T;
    float* part = (float*)(Vs + T);
    float* nmask_s = part + RPB * 5 * (KS - 1);
    const int b = bh / NH, h = bh % NH;
    const int tid = threadIdx.x;
    const __hip_bfloat16* base = cseg + (size_t)b * T * 96;

    if (tid == 0) *nmask_s = 0.f;
    __syncthreads();
    float lnm = 0.f;
    for (int j = tid; j < T; j += BLK) {
        float m = mask[b * T + j];
        float4 kv = bf4_to_f4(base + (size_t)j * 96 + ATTD + h * 4);
        float4 vv = bf4_to_f4(base + (size_t)j * 96 + 2 * ATTD + h * 4);
        kv.x *= m; kv.y *= m; kv.z *= m; kv.w *= m;
        vv.x *= m; vv.y *= m; vv.z *= m; vv.w *= m;
        Ks[j] = kv;
        Vs[j] = vv;
        lnm += 1.f - m;
    }
    lnm = wave_sum(lnm);
    if ((tid & 63) == 0 && lnm != 0.f) atomicAdd(nmask_s, lnm);
    __syncthreads();

    const int r = rb * RPB + (tid % RPB);
    const int ks = tid / RPB;
    const float inv_scale = 0.16439898730535729f;  // 1/sqrt(37)
    float4 qv = bf4_to_f4(base + (size_t)r * 96 + h * 4);
    qv.x *= inv_scale; qv.y *= inv_scale; qv.z *= inv_scale; qv.w *= inv_scale;

    float Sall = 0.f, ox = 0.f, oy = 0.f, oz = 0.f, ow = 0.f;
    constexpr int KC = T / KS;
    const int k0 = ks * KC;
    #pragma unroll 4
    for (int k = k0; k < k0 + KC; k++) {
        float4 kv = Ks[k];
        float4 vv = Vs[k];
        float s = fmaf(qv.x, kv.x, fmaf(qv.y, kv.y, fmaf(qv.z, kv.z, qv.w * kv.w)));
        float e = __expf(s);
        Sall += e;
        ox = fmaf(e, vv.x, ox);
        oy = fmaf(e, vv.y, oy);
        oz = fmaf(e, vv.z, oz);
        ow = fmaf(e, vv.w, ow);
    }
    if (ks > 0) {
        float* p = &part[((ks - 1) * RPB + (tid % RPB)) * 5];
        p[0] = Sall; p[1] = ox; p[2] = oy; p[3] = oz; p[4] = ow;
    }
    __syncthreads();
    if (ks == 0) {
        #pragma unroll
        for (int s2 = 0; s2 < KS - 1; s2++) {
            const float* p = &part[(s2 * RPB + r - rb * RPB) * 5];
            Sall += p[0]; ox += p[1]; oy += p[2]; oz += p[3]; ow += p[4];
        }
        float Sm = Sall - *nmask_s;
        float inv = 1.f / (Sm + 1e-13f * Sall);
        __hip_bfloat16* op = oseg + (size_t)(b * T + r) * ATTD + h * 4;
        op[0] = __float2bfloat16(ox * inv);
        op[1] = __float2bfloat16(oy * inv);
        op[2] = __float2bfloat16(oz * inv);
        op[3] = __float2bfloat16(ow * inv);
    }
}

// ---------------- merged q+d attention: blocks [0,256) = q, [256,1280) = d ----------------
__global__ __launch_bounds__(512) void attn_both(const __hip_bfloat16* __restrict__ cbf,
                                                 const float* __restrict__ mask_q,
                                                 const float* __restrict__ mask_d,
                                                 __hip_bfloat16* __restrict__ o32) {
    __shared__ __align__(16) char smem[24576];
    int blk = blockIdx.x;
    if (blk < BATCH * NH) {
        attn_body<LQ, 64, 8>(cbf, mask_q, o32, blk, 0, smem);
    } else {
        int bid = blk - BATCH * NH;
        attn_body<LD, 128, 4>(cbf + (size_t)MQ * 96, mask_d, o32 + (size_t)MQ * ATTD,
                              bid >> 2, bid & 3, smem);
    }
}

// ---------------- mix + L2 normalize (bf16 in/out, stride 320), uint2-vectorized ----------
__global__ __launch_bounds__(256) void mixnorm_bf(const __hip_bfloat16* __restrict__ x,
                                                  const __hip_bfloat16* __restrict__ xc,
                                                  const float* __restrict__ mask,
                                                  const float* __restrict__ mixer,
                                                  __hip_bfloat16* __restrict__ out) {
    int wid = (blockIdx.x * 256 + threadIdx.x) >> 6;
    int lane = threadIdx.x & 63;
    float mixv = mixer[0];
    float mval = mask[wid];
    const __hip_bfloat16* xr = x + (size_t)wid * STR;
    const __hip_bfloat16* xcr = xc + (size_t)wid * STR;
    const bool hasB = lane < 11;
    float vA[4], vB[4];
    float s2 = 0.f;
    {
        float4 xa = bf4_to_f4(xr + lane * 4);
        float4 xca = bf4_to_f4(xcr + lane * 4);
        vA[0] = (mixv * xa.x + (1.f - mixv) * xca.x) * mval;
        vA[1] = (mixv * xa.y + (1.f - mixv) * xca.y) * mval;
        vA[2] = (mixv * xa.z + (1.f - mixv) * xca.z) * mval;
        vA[3] = (mixv * xa.w + (1.f - mixv) * xca.w) * mval;
        s2 += vA[0] * vA[0] + vA[1] * vA[1] + vA[2] * vA[2] + vA[3] * vA[3];
    }
    if (hasB) {
        int c = 64 + lane;
        float4 xa = bf4_to_f4(xr + c * 4);
        float4 xca = bf4_to_f4(xcr + c * 4);
        vB[0] = (mixv * xa.x + (1.f - mixv) * xca.x) * mval;
        vB[1] = (mixv * xa.y + (1.f - mixv) * xca.y) * mval;
        vB[2] = (mixv * xa.z + (1.f - mixv) * xca.z) * mval;
        vB[3] = (mixv * xa.w + (1.f - mixv) * xca.w) * mval;
        s2 += vB[0] * vB[0] + vB[1] * vB[1] + vB[2] * vB[2] + vB[3] * vB[3];
    }
    s2 = wave_sum(s2);
    float inv = 1.f / (sqrtf(s2) + 1e-13f);
    __hip_bfloat16* o = out + (size_t)wid * STR;
    {
        uint2 u;
        u.x = (unsigned)f2bfu(vA[0] * inv) | ((unsigned)f2bfu(vA[1] * inv) << 16);
        u.y = (unsigned)f2bfu(vA[2] * inv) | ((unsigned)f2bfu(vA[3] * inv) << 16);
        *(uint2*)(o + lane * 4) = u;
    }
    if (hasB) {
        int c = 64 + lane;
        uint2 u;
        u.x = (unsigned)f2bfu(vB[0] * inv) | ((unsigned)f2bfu(vB[1] * inv) << 16);
        u.y = (unsigned)f2bfu(vB[2] * inv) | ((unsigned)f2bfu(vB[3] * inv) << 16);
        *(uint2*)(o + c * 4) = u;
    }
}

// ---------------- kernel pooling with grouped exp-recurrence ----------------
__global__ __launch_bounds__(256) void pool_kernel(const float* __restrict__ Cos,
                                                   const float* __restrict__ mask_q,
                                                   const float* __restrict__ mask_d,
                                                   const float* __restrict__ nn_scaler,
                                                   float* __restrict__ lp) {
    int wid = (blockIdx.x * 256 + threadIdx.x) >> 6;
    int lane = threadIdx.x & 63;
    int b = wid >> 6, qi = wid & 63;
    const float* crow = Cos + ((size_t)b * LQ + qi) * LD;
    const float* md = mask_d + b * LD;
    float acc[NK];
    #pragma unroll
    for (int k = 0; k < NK; k++) acc[k] = 0.f;
    #pragma unroll
    for (int rr = 0; rr < LD / 64; rr++) {
        int dj = rr * 64 + lane;
        float m = md[dj];
        if (m != 0.f) {
            float cv = crow[dj];
            float d0 = cv - 1.0f;
            acc[0] += __expf(d0 * d0 * -500000.0f);
            #pragma unroll
            for (int g = 0; g < 4; g++) {
                float mu_a = 0.95f - 0.5f * g;
                float dc = cv - mu_a;
                float t = __expf(dc * dc * -50.0f);
                float r = __expf(fmaf(-10.0f, dc, -0.5f));
                #pragma unroll
                for (int j = 0; j < 5; j++) {
                    acc[1 + 5 * g + j] += t;
                    t *= r;
                    r *= 0.36787944117144233f;   // e^-1
                }
            }
        }
    }
    float mq = mask_q[b * LQ + qi];
    float ns = nn_scaler[0];
    #pragma unroll
    for (int k = 0; k < NK; k++) {
        float s = wave_sum(acc[k]);
        if (lane == 0) lp[((size_t)b * LQ + qi) * NK + k] = log2f(fmaxf(s, 1e-10f)) * ns * mq;
    }
}

// ---------------- final: out[b] = sum_k dense_w[k] * sum_qi lp[b,qi,k] ----------------
__global__ void final_kernel(const float* __restrict__ lp, const float* __restrict__ dense_w,
                             float* __restrict__ out) {
    int b = blockIdx.x;
    int t = threadIdx.x;  // 64 threads
    float s = 0.f;
    if (t < NK) {
        for (int qi = 0; qi < LQ; qi++) s += lp[((size_t)b * LQ + qi) * NK + t];
        s *= dense_w[t];
    }
    s = wave_sum(s);
    if (t == 0) out[b] = s;
}

extern "C" void kernel_launch(void* const* d_in, const int* in_sizes, int n_in,
                              void* d_out, int out_size, void* d_ws, size_t ws_size,
                              hipStream_t stream) {
    (void)in_sizes; (void)n_in; (void)out_size; (void)ws_size;
    const float* q_embed  = (const float*)d_in[0];
    const float* d_embed  = (const float*)d_in[1];
    const float* mask_q   = (const float*)d_in[2];
    const float* mask_d   = (const float*)d_in[3];
    const float* mixer    = (const float*)d_in[4];
    const float* nn_scaler= (const float*)d_in[5];
    const float* ff_w1    = (const float*)d_in[6];
    const float* ff_b1    = (const float*)d_in[7];
    const float* ff_w2    = (const float*)d_in[8];
    const float* ff_b2    = (const float*)d_in[9];
    const float* ln1_g    = (const float*)d_in[10];
    const float* ln1_b    = (const float*)d_in[11];
    const float* att_w    = (const float*)d_in[12];
    const float* att_b    = (const float*)d_in[13];
    const float* out_w    = (const float*)d_in[14];
    const float* out_b    = (const float*)d_in[15];
    const float* ln2_g    = (const float*)d_in[16];
    const float* ln2_b    = (const float*)d_in[17];
    const float* dense_w  = (const float*)d_in[18];
    float* out = (float*)d_out;

    // ---------------- workspace layout ----------------
    float* ws   = (float*)d_ws;
    float* cosb = ws;                         // 32*64*512 = 1,048,576 fp32
    float* lp   = cosb + 1048576;             // 43,008
    float* mall = lp + 43008;                 // 18,432
    __hip_bfloat16* xbf   = (__hip_bfloat16*)(mall + MALL);   // MALL*STR masked embeddings
    __hip_bfloat16* xcbf  = xbf  + (size_t)MALL * STR;        // layer-0 output
    __hip_bfloat16* xc2bf = xcbf + (size_t)MALL * STR;        // layer-1 output
    __hip_bfloat16* hbf   = xc2bf + (size_t)MALL * STR;       // LN1 out; later qdn
    __hip_bfloat16* cbf   = hbf  + (size_t)MALL * STR;        // MALL*96
    __hip_bfloat16* o32bf = cbf  + (size_t)MALL * 96;         // MALL*ATTD
    __hip_bfloat16* w1t   = o32bf + (size_t)MALL * ATTD;      // 2*112*320
    __hip_bfloat16* w2t   = w1t + 2 * 112 * 320;              // 2*304*128
    __hip_bfloat16* awt   = w2t + 2 * 304 * 128;              // 2*96*320
    __hip_bfloat16* owt   = awt + 2 * 96 * 320;               // 2*304*32

    // 0. fused prep: masked embeddings + masks + all weights (one kernel)
    const int PREP_N = MALL * EMB + 2 * 112 * 320 + 2 * 304 * 128 + 2 * 96 * 320 + 2 * 304 * 32;
    prep_all<<<(PREP_N + 255) / 256, 256, 0, stream>>>(
        q_embed, d_embed, mask_q, mask_d, ff_w1, ff_w2, att_w, out_w,
        xbf, mall, w1t, w2t, awt, owt);

    // 1. merged encoder: [enc_fused -> attn_both -> OUT+LN2] per layer
    const __hip_bfloat16* xcur = xbf;
    for (int l = 0; l < 2; l++) {
        __hip_bfloat16* xout = (l == 0) ? xcbf : xc2bf;
        enc_fused<<<MALL / 64, 256, 0, stream>>>(
            xcur,
            w1t + (size_t)l * 112 * 320, ff_b1 + l * FFH,
            w2t + (size_t)l * 304 * 128, ff_b2 + l * EMB,
            ln1_g + l * EMB, ln1_b + l * EMB,
            awt + (size_t)l * 96 * 320, att_b + l * 96,
            hbf, cbf);
        attn_both<<<BATCH * NH + BATCH * NH * (LD / 128), 512, 0, stream>>>(
            cbf, mask_q, mask_d, o32bf);
        gemm_ln_direct<1, 32, 32, STR><<<MALL / 64, 256, 0, stream>>>(
            o32bf, owt + (size_t)l * 304 * 32, out_b + l * EMB, hbf,
            ln2_g + l * EMB, ln2_b + l * EMB, xout);
        xcur = xout;
    }

    // 2. mix + normalize -> hbf (free after encoder)
    mixnorm_bf<<<MALL / 4, 256, 0, stream>>>(xbf, xc2bf, mall, mixer, hbf);

    // 3. cosine matrix via MFMA -> cosb
    cos_mfma<<<dim3(LD / 64, BATCH), 256, 0, stream>>>(hbf, hbf + (size_t)MQ * STR, cosb);

    // 4. kernel pooling (grouped exp-recurrence)
    pool_kernel<<<(BATCH * LQ) / 4, 256, 0, stream>>>(cosb, mask_q, mask_d, nn_scaler, lp);

    // 5. final projection
    final_kernel<<<BATCH, 64, 0, stream>>>(lp, dense_w, out);
}

// Round 16
// 237.210 us; speedup vs baseline: 1.2302x; 1.0564x over previous
//
#include <hip/hip_runtime.h>
#include <hip/hip_bf16.h>

// Problem constants
#define BATCH 32
#define LQ 64
#define LD 512
#define EMB 300
#define FFH 100
#define ATTD 32
#define NH 8
#define NK 21
#define MQ (BATCH * LQ)          // 2048 query tokens
#define MD (BATCH * LD)          // 16384 doc tokens
#define MALL (MQ + MD)           // 18432 merged tokens

typedef __attribute__((ext_vector_type(8))) short bf16x8;
typedef __attribute__((ext_vector_type(4))) float f32x4;

__device__ __forceinline__ float wave_sum(float v) {
    #pragma unroll
    for (int off = 32; off > 0; off >>= 1) v += __shfl_xor(v, off);
    return v;
}

__device__ __forceinline__ float bf2f(__hip_bfloat16 h) { return __bfloat162float(h); }

// 4 consecutive bf16 -> float4 (8B-aligned source)
__device__ __forceinline__ float4 bf4_to_f4(const __hip_bfloat16* p) {
    uint2 u = *(const uint2*)p;
    float4 f;
    f.x = __uint_as_float((u.x & 0xffffu) << 16);
    f.y = __uint_as_float(u.x & 0xffff0000u);
    f.z = __uint_as_float((u.y & 0xffffu) << 16);
    f.w = __uint_as_float(u.y & 0xffff0000u);
    return f;
}

__device__ __forceinline__ unsigned short f2bfu(float x) {
    __hip_bfloat16 h = __float2bfloat16(x);
    return *(unsigned short*)&h;
}

// ---------------- fused prep: masked embeddings (float4 reads) + masks + all weights -----
// xbf[tok*300+c] = bf16(emb*mask) ; w1t [l][100][300], w2t [l][320][128] zero-padded,
// awt [l][96][300], owt [l][320][32] zero-padded.
__global__ void prep_all(const float* __restrict__ qe, const float* __restrict__ de,
                         const float* __restrict__ mq, const float* __restrict__ md,
                         const float* __restrict__ w1, const float* __restrict__ w2,
                         const float* __restrict__ aw, const float* __restrict__ ow,
                         __hip_bfloat16* __restrict__ xbf, float* __restrict__ mall,
                         __hip_bfloat16* __restrict__ w1t, __hip_bfloat16* __restrict__ w2t,
                         __hip_bfloat16* __restrict__ awt, __hip_bfloat16* __restrict__ owt) {
    int i = blockIdx.x * blockDim.x + threadIdx.x;
    const int NQ4 = MALL * (EMB / 4);             // 1,382,400 float4 chunks
    if (i < NQ4) {
        int tok = i / (EMB / 4), c4 = (i % (EMB / 4)) * 4;
        float m;
        float4 v;
        if (tok < MQ) {
            m = mq[tok];
            v = *(const float4*)(qe + (size_t)tok * EMB + c4);
        } else {
            m = md[tok - MQ];
            v = *(const float4*)(de + (size_t)(tok - MQ) * EMB + c4);
        }
        uint2 u;
        u.x = (unsigned)f2bfu(v.x * m) | ((unsigned)f2bfu(v.y * m) << 16);
        u.y = (unsigned)f2bfu(v.z * m) | ((unsigned)f2bfu(v.w * m) << 16);
        *(uint2*)(xbf + (size_t)tok * EMB + c4) = u;
        if (c4 == 0) mall[tok] = m;
        return;
    }
    int j = i - NQ4;
    if (j < 2 * EMB * FFH) {                      // w1t: w1[l][k][n] -> [l][n][k]
        int l = j / (EMB * FFH), r = j % (EMB * FFH);
        int k = r / FFH, n = r % FFH;
        w1t[(size_t)l * FFH * EMB + (size_t)n * EMB + k] = __float2bfloat16(w1[j]);
        return;
    }
    j -= 2 * EMB * FFH;
    if (j < 2 * 320 * 128) {                      // w2t zero-padded [l][320][128]
        int l = j / (320 * 128), r = j % (320 * 128);
        int n = r / 128, k = r % 128;
        float v = (n < EMB && k < FFH) ? w2[(size_t)l * FFH * EMB + (size_t)k * EMB + n] : 0.f;
        w2t[j] = __float2bfloat16(v);
        return;
    }
    j -= 2 * 320 * 128;
    if (j < 2 * EMB * 96) {                       // awt: aw[l][k][n] -> [l][n][k]
        int l = j / (EMB * 96), r = j % (EMB * 96);
        int k = r / 96, n = r % 96;
        awt[(size_t)l * 96 * EMB + (size_t)n * EMB + k] = __float2bfloat16(aw[j]);
        return;
    }
    j -= 2 * EMB * 96;
    if (j < 2 * 320 * 32) {                       // owt zero-padded [l][320][32]
        int l = j / (320 * 32), r = j % (320 * 32);
        int n = r / 32, k = r % 32;
        float v = (n < EMB) ? ow[(size_t)l * ATTD * EMB + (size_t)k * EMB + n] : 0.f;
        owt[j] = __float2bfloat16(v);
    }
}

// ---------------- shared staging helper: 8 bf16 of one row ----------------
__device__ __forceinline__ void stage_row8(const __hip_bfloat16* __restrict__ src, bool rowvalid,
                                           int K, int gk, __hip_bfloat16* dst) {
    if (rowvalid && gk + 8 <= K) {
        const uint2* p = (const uint2*)(src + gk);
        uint2 a = p[0], b = p[1];
        *(uint2*)dst = a;
        *(uint2*)(dst + 4) = b;
    } else {
        #pragma unroll
        for (int j = 0; j < 8; j++)
            dst[j] = (rowvalid && gk + j < K) ? src[gk + j] : __float2bfloat16(0.f);
    }
}

// ---------------- MFMA bf16 GEMM: Cb[M,Ns] = A[M,K] @ Bt[Nr,K]^T + bias (+relu) ---------
// 64x64 tile, 4 waves (2x2), 2x2 mfma_f32_16x16x32_bf16 fragments.
// D layout (m89-verified): col = lane&15, row = (lane>>4)*4 + reg.
template <bool RELU>
__global__ __launch_bounds__(256) void gemm_mfma(const __hip_bfloat16* __restrict__ A,
                                                 const __hip_bfloat16* __restrict__ Bt,
                                                 const float* __restrict__ bias,
                                                 __hip_bfloat16* __restrict__ Cb,
                                                 int M, int Nr, int Ns, int K) {
    __shared__ __align__(16) __hip_bfloat16 As[64][40];
    __shared__ __align__(16) __hip_bfloat16 Bs[64][40];
    const int tid = threadIdx.x;
    const int m0 = blockIdx.y * 64, n0 = blockIdx.x * 64;
    const int lane = tid & 63;
    const int wv = tid >> 6;
    const int wm = wv >> 1, wn = wv & 1;
    const int l15 = lane & 15, lg = lane >> 4;
    const int srow = tid >> 2, sk8 = (tid & 3) * 8;
    f32x4 acc[2][2] = {};
    const int NS = (K + 31) >> 5;
    const __hip_bfloat16* arow = A + (size_t)(m0 + srow) * K;
    const bool bvalid = (n0 + srow) < Nr;
    const __hip_bfloat16* brow = Bt + (size_t)(n0 + srow) * K;

    for (int s = 0; s < NS; s++) {
        const int gk = (s << 5) + sk8;
        if (s) __syncthreads();
        stage_row8(arow, true, K, gk, &As[srow][sk8]);
        stage_row8(brow, bvalid, K, gk, &Bs[srow][sk8]);
        __syncthreads();
        bf16x8 af0 = *(const bf16x8*)&As[wm * 32 + l15][lg * 8];
        bf16x8 af1 = *(const bf16x8*)&As[wm * 32 + 16 + l15][lg * 8];
        bf16x8 bf0 = *(const bf16x8*)&Bs[wn * 32 + l15][lg * 8];
        bf16x8 bf1 = *(const bf16x8*)&Bs[wn * 32 + 16 + l15][lg * 8];
        acc[0][0] = __builtin_amdgcn_mfma_f32_16x16x32_bf16(af0, bf0, acc[0][0], 0, 0, 0);
        acc[0][1] = __builtin_amdgcn_mfma_f32_16x16x32_bf16(af0, bf1, acc[0][1], 0, 0, 0);
        acc[1][0] = __builtin_amdgcn_mfma_f32_16x16x32_bf16(af1, bf0, acc[1][0], 0, 0, 0);
        acc[1][1] = __builtin_amdgcn_mfma_f32_16x16x32_bf16(af1, bf1, acc[1][1], 0, 0, 0);
    }

    #pragma unroll
    for (int fc = 0; fc < 2; fc++) {
        int col = n0 + wn * 32 + fc * 16 + l15;
        if (col >= Ns) continue;
        float bs = (col < Nr) ? bias[col] : 0.f;
        #pragma unroll
        for (int fr = 0; fr < 2; fr++) {
            int rbase = m0 + wm * 32 + fr * 16 + lg * 4;
            #pragma unroll
            for (int r = 0; r < 4; r++) {
                float v = acc[fr][fc][r] + bs;
                if (RELU) v = fmaxf(v, 0.f);
                Cb[(size_t)(rbase + r) * Ns + col] = __float2bfloat16(v);
            }
        }
    }
}

// ---------------- DIRECT-OPERAND GEMM + residual + LayerNorm (N = 300, no LDS) ----------
// One wave owns 16 rows x all 304 cols (19 fragments); operands direct from global.
template <int NSTEP, int KSTR, int ASTR>
__global__ __launch_bounds__(256) void gemm_ln_direct(const __hip_bfloat16* __restrict__ A,
                                                      const __hip_bfloat16* __restrict__ Bt,
                                                      const float* __restrict__ bias,
                                                      const __hip_bfloat16* __restrict__ Res,
                                                      const float* __restrict__ g,
                                                      const float* __restrict__ beta,
                                                      __hip_bfloat16* __restrict__ Y) {
    const int tid = threadIdx.x;
    const int wv = tid >> 6;
    const int lane = tid & 63;
    const int l15 = lane & 15, lg = lane >> 4;
    const int m0 = blockIdx.x * 64 + wv * 16;

    f32x4 acc[19];
    #pragma unroll
    for (int fc = 0; fc < 19; fc++) acc[fc] = (f32x4){0.f, 0.f, 0.f, 0.f};

    #pragma unroll
    for (int ks = 0; ks < NSTEP; ks++) {
        const int kb = ks * 32 + lg * 8;
        bf16x8 af = *(const bf16x8*)(A + (size_t)(m0 + l15) * ASTR + kb);
        #pragma unroll
        for (int fc = 0; fc < 19; fc++) {
            bf16x8 bf = *(const bf16x8*)(Bt + (size_t)(fc * 16 + l15) * KSTR + kb);
            acc[fc] = __builtin_amdgcn_mfma_f32_16x16x32_bf16(af, bf, acc[fc], 0, 0, 0);
        }
    }

    float rs[4] = {0.f, 0.f, 0.f, 0.f};
    #pragma unroll
    for (int fc = 0; fc < 19; fc++) {
        int col = fc * 16 + l15;
        bool valid = col < EMB;
        float bs = valid ? bias[col] : 0.f;
        #pragma unroll
        for (int r = 0; r < 4; r++) {
            float v = 0.f;
            if (valid) v = acc[fc][r] + bs + bf2f(Res[(size_t)(m0 + lg * 4 + r) * EMB + col]);
            acc[fc][r] = v;
            rs[r] += v;
        }
    }
    #pragma unroll
    for (int r = 0; r < 4; r++)
        #pragma unroll
        for (int off = 1; off < 16; off <<= 1)
            rs[r] += __shfl_xor(rs[r], off);
    float mean[4], invv[4];
    #pragma unroll
    for (int r = 0; r < 4; r++) mean[r] = rs[r] * (1.f / EMB);

    float rq[4] = {0.f, 0.f, 0.f, 0.f};
    #pragma unroll
    for (int fc = 0; fc < 19; fc++) {
        int col = fc * 16 + l15;
        if (col < EMB) {
            #pragma unroll
            for (int r = 0; r < 4; r++) {
                float d = acc[fc][r] - mean[r];
                rq[r] += d * d;
            }
        }
    }
    #pragma unroll
    for (int r = 0; r < 4; r++) {
        #pragma unroll
        for (int off = 1; off < 16; off <<= 1)
            rq[r] += __shfl_xor(rq[r], off);
        float stdv = sqrtf(rq[r] * (1.f / (EMB - 1)));
        invv[r] = 1.f / (stdv + 1e-6f);
    }
    #pragma unroll
    for (int fc = 0; fc < 19; fc++) {
        int col = fc * 16 + l15;
        if (col >= EMB) continue;
        float gv = g[col], bv = beta[col];
        #pragma unroll
        for (int r = 0; r < 4; r++) {
            float y = gv * (acc[fc][r] - mean[r]) * invv[r] + bv;
            Y[(size_t)(m0 + lg * 4 + r) * EMB + col] = __float2bfloat16(y);
        }
    }
}

// ---------------- batched MFMA cos GEMM: Cos[b] = Qn[b] (64xK) @ Dn[b] (512xK)^T (fp32 out)
__global__ __launch_bounds__(256) void cos_mfma(const __hip_bfloat16* __restrict__ Qn,
                                                const __hip_bfloat16* __restrict__ Dn,
                                                float* __restrict__ Cos) {
    __shared__ __align__(16) __hip_bfloat16 As[64][40];
    __shared__ __align__(16) __hip_bfloat16 Bs[64][40];
    const int b = blockIdx.y;
    const int n0 = blockIdx.x * 64;
    const int tid = threadIdx.x;
    const int lane = tid & 63;
    const int wv = tid >> 6;
    const int wm = wv >> 1, wn = wv & 1;
    const int l15 = lane & 15, lg = lane >> 4;
    const int srow = tid >> 2, sk8 = (tid & 3) * 8;
    f32x4 acc[2][2] = {};
    const int NS = (EMB + 31) >> 5;   // 10
    const __hip_bfloat16* arow = Qn + ((size_t)b * LQ + srow) * EMB;
    const __hip_bfloat16* brow = Dn + ((size_t)b * LD + n0 + srow) * EMB;

    for (int s = 0; s < NS; s++) {
        const int gk = (s << 5) + sk8;
        if (s) __syncthreads();
        stage_row8(arow, true, EMB, gk, &As[srow][sk8]);
        stage_row8(brow, true, EMB, gk, &Bs[srow][sk8]);
        __syncthreads();
        bf16x8 af0 = *(const bf16x8*)&As[wm * 32 + l15][lg * 8];
        bf16x8 af1 = *(const bf16x8*)&As[wm * 32 + 16 + l15][lg * 8];
        bf16x8 bf0 = *(const bf16x8*)&Bs[wn * 32 + l15][lg * 8];
        bf16x8 bf1 = *(const bf16x8*)&Bs[wn * 32 + 16 + l15][lg * 8];
        acc[0][0] = __builtin_amdgcn_mfma_f32_16x16x32_bf16(af0, bf0, acc[0][0], 0, 0, 0);
        acc[0][1] = __builtin_amdgcn_mfma_f32_16x16x32_bf16(af0, bf1, acc[0][1], 0, 0, 0);
        acc[1][0] = __builtin_amdgcn_mfma_f32_16x16x32_bf16(af1, bf0, acc[1][0], 0, 0, 0);
        acc[1][1] = __builtin_amdgcn_mfma_f32_16x16x32_bf16(af1, bf1, acc[1][1], 0, 0, 0);
    }

    float* cb = Cos + (size_t)b * LQ * LD;
    #pragma unroll
    for (int fc = 0; fc < 2; fc++) {
        int col = n0 + wn * 32 + fc * 16 + l15;
        #pragma unroll
        for (int fr = 0; fr < 2; fr++) {
            int rbase = wm * 32 + fr * 16 + lg * 4;
            #pragma unroll
            for (int r = 0; r < 4; r++) {
                cb[(size_t)(rbase + r) * LD + col] = acc[fr][fc][r];
            }
        }
    }
}

// ---------------- attention body (templated), smem carved by caller ----------------
template <int T, int RPB, int KS>
__device__ __forceinline__ void attn_body(const __hip_bfloat16* __restrict__ cseg,
                                          const float* __restrict__ mask,
                                          __hip_bfloat16* __restrict__ oseg,
                                          int bh, int rb, char* smem) {
    constexpr int BLK = 512;
    float4* Ks = (float4*)smem;
    float4* Vs = Ks + T;
    float* part = (float*)(Vs + T);
    float* nmask_s = part + RPB * 5 * (KS - 1);
    const int b = bh / NH, h = bh % NH;
    const int tid = threadIdx.x;
    const __hip_bfloat16* base = cseg + (size_t)b * T * 96;

    if (tid == 0) *nmask_s = 0.f;
    __syncthreads();
    float lnm = 0.f;
    for (int j = tid; j < T; j += BLK) {
        float m = mask[b * T + j];
        float4 kv = bf4_to_f4(base + (size_t)j * 96 + ATTD + h * 4);
        float4 vv = bf4_to_f4(base + (size_t)j * 96 + 2 * ATTD + h * 4);
        kv.x *= m; kv.y *= m; kv.z *= m; kv.w *= m;
        vv.x *= m; vv.y *= m; vv.z *= m; vv.w *= m;
        Ks[j] = kv;
        Vs[j] = vv;
        lnm += 1.f - m;
    }
    lnm = wave_sum(lnm);
    if ((tid & 63) == 0 && lnm != 0.f) atomicAdd(nmask_s, lnm);
    __syncthreads();

    const int r = rb * RPB + (tid % RPB);
    const int ks = tid / RPB;
    const float inv_scale = 0.16439898730535729f;  // 1/sqrt(37)
    float4 qv = bf4_to_f4(base + (size_t)r * 96 + h * 4);
    qv.x *= inv_scale; qv.y *= inv_scale; qv.z *= inv_scale; qv.w *= inv_scale;

    float Sall = 0.f, ox = 0.f, oy = 0.f, oz = 0.f, ow = 0.f;
    constexpr int KC = T / KS;
    const int k0 = ks * KC;
    #pragma unroll 4
    for (int k = k0; k < k0 + KC; k++) {
        float4 kv = Ks[k];
        float4 vv = Vs[k];
        float s = fmaf(qv.x, kv.x, fmaf(qv.y, kv.y, fmaf(qv.z, kv.z, qv.w * kv.w)));
        float e = __expf(s);
        Sall += e;
        ox = fmaf(e, vv.x, ox);
        oy = fmaf(e, vv.y, oy);
        oz = fmaf(e, vv.z, oz);
        ow = fmaf(e, vv.w, ow);
    }
    if (ks > 0) {
        float* p = &part[((ks - 1) * RPB + (tid % RPB)) * 5];
        p[0] = Sall; p[1] = ox; p[2] = oy; p[3] = oz; p[4] = ow;
    }
    __syncthreads();
    if (ks == 0) {
        #pragma unroll
        for (int s2 = 0; s2 < KS - 1; s2++) {
            const float* p = &part[(s2 * RPB + r - rb * RPB) * 5];
            Sall += p[0]; ox += p[1]; oy += p[2]; oz += p[3]; ow += p[4];
        }
        float Sm = Sall - *nmask_s;
        float inv = 1.f / (Sm + 1e-13f * Sall);
        __hip_bfloat16* op = oseg + (size_t)(b * T + r) * ATTD + h * 4;
        op[0] = __float2bfloat16(ox * inv);
        op[1] = __float2bfloat16(oy * inv);
        op[2] = __float2bfloat16(oz * inv);
        op[3] = __float2bfloat16(ow * inv);
    }
}

// ---------------- merged q+d attention: blocks [0,256) = q, [256,1280) = d ----------------
__global__ __launch_bounds__(512) void attn_both(const __hip_bfloat16* __restrict__ cbf,
                                                 const float* __restrict__ mask_q,
                                                 const float* __restrict__ mask_d,
                                                 __hip_bfloat16* __restrict__ o32) {
    __shared__ __align__(16) char smem[24576];
    int blk = blockIdx.x;
    if (blk < BATCH * NH) {
        attn_body<LQ, 64, 8>(cbf, mask_q, o32, blk, 0, smem);
    } else {
        int bid = blk - BATCH * NH;
        attn_body<LD, 128, 4>(cbf + (size_t)MQ * 96, mask_d, o32 + (size_t)MQ * ATTD,
                              bid >> 2, bid & 3, smem);
    }
}

// ---------------- mix + L2 normalize (bf16 in/out), uint2-vectorized ----------------
__global__ __launch_bounds__(256) void mixnorm_bf(const __hip_bfloat16* __restrict__ x,
                                                  const __hip_bfloat16* __restrict__ xc,
                                                  const float* __restrict__ mask,
                                                  const float* __restrict__ mixer,
                                                  __hip_bfloat16* __restrict__ out) {
    int wid = (blockIdx.x * 256 + threadIdx.x) >> 6;
    int lane = threadIdx.x & 63;
    float mixv = mixer[0];
    float mval = mask[wid];
    const __hip_bfloat16* xr = x + (size_t)wid * EMB;
    const __hip_bfloat16* xcr = xc + (size_t)wid * EMB;
    const bool hasB = lane < 11;
    float vA[4], vB[4];
    float s2 = 0.f;
    {
        float4 xa = bf4_to_f4(xr + lane * 4);
        float4 xca = bf4_to_f4(xcr + lane * 4);
        vA[0] = (mixv * xa.x + (1.f - mixv) * xca.x) * mval;
        vA[1] = (mixv * xa.y + (1.f - mixv) * xca.y) * mval;
        vA[2] = (mixv * xa.z + (1.f - mixv) * xca.z) * mval;
        vA[3] = (mixv * xa.w + (1.f - mixv) * xca.w) * mval;
        s2 += vA[0] * vA[0] + vA[1] * vA[1] + vA[2] * vA[2] + vA[3] * vA[3];
    }
    if (hasB) {
        int c = 64 + lane;
        float4 xa = bf4_to_f4(xr + c * 4);
        float4 xca = bf4_to_f4(xcr + c * 4);
        vB[0] = (mixv * xa.x + (1.f - mixv) * xca.x) * mval;
        vB[1] = (mixv * xa.y + (1.f - mixv) * xca.y) * mval;
        vB[2] = (mixv * xa.z + (1.f - mixv) * xca.z) * mval;
        vB[3] = (mixv * xa.w + (1.f - mixv) * xca.w) * mval;
        s2 += vB[0] * vB[0] + vB[1] * vB[1] + vB[2] * vB[2] + vB[3] * vB[3];
    }
    s2 = wave_sum(s2);
    float inv = 1.f / (sqrtf(s2) + 1e-13f);
    __hip_bfloat16* o = out + (size_t)wid * EMB;
    {
        uint2 u;
        u.x = (unsigned)f2bfu(vA[0] * inv) | ((unsigned)f2bfu(vA[1] * inv) << 16);
        u.y = (unsigned)f2bfu(vA[2] * inv) | ((unsigned)f2bfu(vA[3] * inv) << 16);
        *(uint2*)(o + lane * 4) = u;
    }
    if (hasB) {
        int c = 64 + lane;
        uint2 u;
        u.x = (unsigned)f2bfu(vB[0] * inv) | ((unsigned)f2bfu(vB[1] * inv) << 16);
        u.y = (unsigned)f2bfu(vB[2] * inv) | ((unsigned)f2bfu(vB[3] * inv) << 16);
        *(uint2*)(o + c * 4) = u;
    }
}

// ---------------- kernel pooling with grouped exp-recurrence ----------------
__global__ __launch_bounds__(256) void pool_kernel(const float* __restrict__ Cos,
                                                   const float* __restrict__ mask_q,
                                                   const float* __restrict__ mask_d,
                                                   const float* __restrict__ nn_scaler,
                                                   float* __restrict__ lp) {
    int wid = (blockIdx.x * 256 + threadIdx.x) >> 6;
    int lane = threadIdx.x & 63;
    int b = wid >> 6, qi = wid & 63;
    const float* crow = Cos + ((size_t)b * LQ + qi) * LD;
    const float* md = mask_d + b * LD;
    float acc[NK];
    #pragma unroll
    for (int k = 0; k < NK; k++) acc[k] = 0.f;
    #pragma unroll
    for (int rr = 0; rr < LD / 64; rr++) {
        int dj = rr * 64 + lane;
        float m = md[dj];
        if (m != 0.f) {
            float cv = crow[dj];
            float d0 = cv - 1.0f;
            acc[0] += __expf(d0 * d0 * -500000.0f);
            #pragma unroll
            for (int g = 0; g < 4; g++) {
                float mu_a = 0.95f - 0.5f * g;
                float dc = cv - mu_a;
                float t = __expf(dc * dc * -50.0f);
                float r = __expf(fmaf(-10.0f, dc, -0.5f));
                #pragma unroll
                for (int j = 0; j < 5; j++) {
                    acc[1 + 5 * g + j] += t;
                    t *= r;
                    r *= 0.36787944117144233f;   // e^-1
                }
            }
        }
    }
    float mq = mask_q[b * LQ + qi];
    float ns = nn_scaler[0];
    #pragma unroll
    for (int k = 0; k < NK; k++) {
        float s = wave_sum(acc[k]);
        if (lane == 0) lp[((size_t)b * LQ + qi) * NK + k] = log2f(fmaxf(s, 1e-10f)) * ns * mq;
    }
}

// ---------------- final: out[b] = sum_k dense_w[k] * sum_qi lp[b,qi,k] ----------------
__global__ void final_kernel(const float* __restrict__ lp, const float* __restrict__ dense_w,
                             float* __restrict__ out) {
    int b = blockIdx.x;
    int t = threadIdx.x;  // 64 threads
    float s = 0.f;
    if (t < NK) {
        for (int qi = 0; qi < LQ; qi++) s += lp[((size_t)b * LQ + qi) * NK + t];
        s *= dense_w[t];
    }
    s = wave_sum(s);
    if (t == 0) out[b] = s;
}

extern "C" void kernel_launch(void* const* d_in, const int* in_sizes, int n_in,
                              void* d_out, int out_size, void* d_ws, size_t ws_size,
                              hipStream_t stream) {
    (void)in_sizes; (void)n_in; (void)out_size; (void)ws_size;
    const float* q_embed  = (const float*)d_in[0];
    const float* d_embed  = (const float*)d_in[1];
    const float* mask_q   = (const float*)d_in[2];
    const float* mask_d   = (const float*)d_in[3];
    const float* mixer    = (const float*)d_in[4];
    const float* nn_scaler= (const float*)d_in[5];
    const float* ff_w1    = (const float*)d_in[6];
    const float* ff_b1    = (const float*)d_in[7];
    const float* ff_w2    = (const float*)d_in[8];
    const float* ff_b2    = (const float*)d_in[9];
    const float* ln1_g    = (const float*)d_in[10];
    const float* ln1_b    = (const float*)d_in[11];
    const float* att_w    = (const float*)d_in[12];
    const float* att_b    = (const float*)d_in[13];
    const float* out_w    = (const float*)d_in[14];
    const float* out_b    = (const float*)d_in[15];
    const float* ln2_g    = (const float*)d_in[16];
    const float* ln2_b    = (const float*)d_in[17];
    const float* dense_w  = (const float*)d_in[18];
    float* out = (float*)d_out;

    // ---------------- workspace layout (identical to R13) ----------------
    float* ws   = (float*)d_ws;
    float* cosb = ws;                         // 32*64*512 = 1,048,576 fp32
    float* lp   = cosb + 1048576;             // 43,008
    float* mall = lp + 43008;                 // 18,432
    __hip_bfloat16* xbf   = (__hip_bfloat16*)(mall + MALL);   // MALL*EMB masked embeddings
    __hip_bfloat16* xcbf  = xbf  + (size_t)MALL * EMB;        // layer-0 output
    __hip_bfloat16* xc2bf = xcbf + (size_t)MALL * EMB;        // layer-1 output
    __hip_bfloat16* hbf   = xc2bf + (size_t)MALL * EMB;       // LN1 out; later qdn
    __hip_bfloat16* t1bf  = hbf  + (size_t)MALL * EMB;        // MALL*128 (stride-128, zero-pad)
    __hip_bfloat16* cbf   = t1bf + (size_t)MALL * 128;        // MALL*96
    __hip_bfloat16* o32bf = cbf  + (size_t)MALL * 96;         // MALL*ATTD
    __hip_bfloat16* w1t   = o32bf + (size_t)MALL * ATTD;      // 2*100*300
    __hip_bfloat16* w2t   = w1t + 2 * FFH * EMB;              // 2*320*128 (padded)
    __hip_bfloat16* awt   = w2t + 2 * 320 * 128;              // 2*96*300
    __hip_bfloat16* owt   = awt + 2 * 96 * EMB;               // 2*320*32 (padded)

    // 0. fused prep: masked embeddings (float4 reads) + masks + all weights
    const int PREP_N = MALL * (EMB / 4) + 2 * EMB * FFH + 2 * 320 * 128 + 2 * EMB * 96 + 2 * 320 * 32;
    prep_all<<<(PREP_N + 255) / 256, 256, 0, stream>>>(
        q_embed, d_embed, mask_q, mask_d, ff_w1, ff_w2, att_w, out_w,
        xbf, mall, w1t, w2t, awt, owt);

    // 1. merged encoder (identical to R13)
    const __hip_bfloat16* xcur = xbf;
    for (int l = 0; l < 2; l++) {
        __hip_bfloat16* xout = (l == 0) ? xcbf : xc2bf;
        // FF1: relu(x @ w1 + b1) -> t1bf (stride 128, cols 100..127 zeroed)
        gemm_mfma<true><<<dim3(2, MALL / 64), 256, 0, stream>>>(
            xcur, w1t + (size_t)l * FFH * EMB, ff_b1 + l * FFH, t1bf, MALL, FFH, 128, EMB);
        // FF2 + residual(x) + LN1 -> hbf   (direct, K=128 padded)
        gemm_ln_direct<4, 128, 128><<<MALL / 64, 256, 0, stream>>>(
            t1bf, w2t + (size_t)l * 320 * 128, ff_b2 + l * EMB, xcur,
            ln1_g + l * EMB, ln1_b + l * EMB, hbf);
        // ATT: h @ att_w + att_b -> cbf
        gemm_mfma<false><<<dim3(2, MALL / 64), 256, 0, stream>>>(
            hbf, awt + (size_t)l * 96 * EMB, att_b + l * 96, cbf, MALL, 96, 96, EMB);
        // attention (q + d merged) -> o32bf
        attn_both<<<BATCH * NH + BATCH * NH * (LD / 128), 512, 0, stream>>>(
            cbf, mask_q, mask_d, o32bf);
        // OUT + residual(h) + LN2 -> xout  (direct, K=32)
        gemm_ln_direct<1, 32, 32><<<MALL / 64, 256, 0, stream>>>(
            o32bf, owt + (size_t)l * 320 * 32, out_b + l * EMB, hbf,
            ln2_g + l * EMB, ln2_b + l * EMB, xout);
        xcur = xout;
    }

    // 2. mix + normalize -> hbf (free after encoder)
    mixnorm_bf<<<MALL / 4, 256, 0, stream>>>(xbf, xc2bf, mall, mixer, hbf);

    // 3. cosine matrix via MFMA -> cosb
    cos_mfma<<<dim3(LD / 64, BATCH), 256, 0, stream>>>(hbf, hbf + (size_t)MQ * EMB, cosb);

    // 4. kernel pooling (grouped exp-recurrence)
    pool_kernel<<<(BATCH * LQ) / 4, 256, 0, stream>>>(cosb, mask_q, mask_d, nn_scaler, lp);

    // 5. final projection
    final_kernel<<<BATCH, 64, 0, stream>>>(lp, dense_w, out);
}

// Round 17
// 233.254 us; speedup vs baseline: 1.2511x; 1.0170x over previous
//
#include <hip/hip_runtime.h>
#include <hip/hip_bf16.h>

// Problem constants
#define BATCH 32
#define LQ 64
#define LD 512
#define EMB 300
#define FFH 100
#define ATTD 32
#define NH 8
#define NK 21
#define MQ (BATCH * LQ)          // 2048 query tokens
#define MD (BATCH * LD)          // 16384 doc tokens
#define MALL (MQ + MD)           // 18432 merged tokens

typedef __attribute__((ext_vector_type(8))) short bf16x8;
typedef __attribute__((ext_vector_type(4))) float f32x4;

__device__ __forceinline__ float wave_sum(float v) {
    #pragma unroll
    for (int off = 32; off > 0; off >>= 1) v += __shfl_xor(v, off);
    return v;
}

__device__ __forceinline__ float bf2f(__hip_bfloat16 h) { return __bfloat162float(h); }

// 4 consecutive bf16 -> float4 (8B-aligned source)
__device__ __forceinline__ float4 bf4_to_f4(const __hip_bfloat16* p) {
    uint2 u = *(const uint2*)p;
    float4 f;
    f.x = __uint_as_float((u.x & 0xffffu) << 16);
    f.y = __uint_as_float(u.x & 0xffff0000u);
    f.z = __uint_as_float((u.y & 0xffffu) << 16);
    f.w = __uint_as_float(u.y & 0xffff0000u);
    return f;
}

__device__ __forceinline__ unsigned short f2bfu(float x) {
    __hip_bfloat16 h = __float2bfloat16(x);
    return *(unsigned short*)&h;
}

// ---------------- fused prep: masked embeddings (float4 reads) + masks + all weights -----
__global__ void prep_all(const float* __restrict__ qe, const float* __restrict__ de,
                         const float* __restrict__ mq, const float* __restrict__ md,
                         const float* __restrict__ w1, const float* __restrict__ w2,
                         const float* __restrict__ aw, const float* __restrict__ ow,
                         __hip_bfloat16* __restrict__ xbf, float* __restrict__ mall,
                         __hip_bfloat16* __restrict__ w1t, __hip_bfloat16* __restrict__ w2t,
                         __hip_bfloat16* __restrict__ awt, __hip_bfloat16* __restrict__ owt) {
    int i = blockIdx.x * blockDim.x + threadIdx.x;
    const int NQ4 = MALL * (EMB / 4);             // 1,382,400 float4 chunks
    if (i < NQ4) {
        int tok = i / (EMB / 4), c4 = (i % (EMB / 4)) * 4;
        float m;
        float4 v;
        if (tok < MQ) {
            m = mq[tok];
            v = *(const float4*)(qe + (size_t)tok * EMB + c4);
        } else {
            m = md[tok - MQ];
            v = *(const float4*)(de + (size_t)(tok - MQ) * EMB + c4);
        }
        uint2 u;
        u.x = (unsigned)f2bfu(v.x * m) | ((unsigned)f2bfu(v.y * m) << 16);
        u.y = (unsigned)f2bfu(v.z * m) | ((unsigned)f2bfu(v.w * m) << 16);
        *(uint2*)(xbf + (size_t)tok * EMB + c4) = u;
        if (c4 == 0) mall[tok] = m;
        return;
    }
    int j = i - NQ4;
    if (j < 2 * EMB * FFH) {                      // w1t: w1[l][k][n] -> [l][n][k]
        int l = j / (EMB * FFH), r = j % (EMB * FFH);
        int k = r / FFH, n = r % FFH;
        w1t[(size_t)l * FFH * EMB + (size_t)n * EMB + k] = __float2bfloat16(w1[j]);
        return;
    }
    j -= 2 * EMB * FFH;
    if (j < 2 * 320 * 128) {                      // w2t zero-padded [l][320][128]
        int l = j / (320 * 128), r = j % (320 * 128);
        int n = r / 128, k = r % 128;
        float v = (n < EMB && k < FFH) ? w2[(size_t)l * FFH * EMB + (size_t)k * EMB + n] : 0.f;
        w2t[j] = __float2bfloat16(v);
        return;
    }
    j -= 2 * 320 * 128;
    if (j < 2 * EMB * 96) {                       // awt: aw[l][k][n] -> [l][n][k]
        int l = j / (EMB * 96), r = j % (EMB * 96);
        int k = r / 96, n = r % 96;
        awt[(size_t)l * 96 * EMB + (size_t)n * EMB + k] = __float2bfloat16(aw[j]);
        return;
    }
    j -= 2 * EMB * 96;
    if (j < 2 * 320 * 32) {                       // owt zero-padded [l][320][32]
        int l = j / (320 * 32), r = j % (320 * 32);
        int n = r / 32, k = r % 32;
        float v = (n < EMB) ? ow[(size_t)l * ATTD * EMB + (size_t)k * EMB + n] : 0.f;
        owt[j] = __float2bfloat16(v);
    }
}

// ---------------- shared staging helper: 8 bf16 of one row ----------------
__device__ __forceinline__ void stage_row8(const __hip_bfloat16* __restrict__ src, bool rowvalid,
                                           int K, int gk, __hip_bfloat16* dst) {
    if (rowvalid && gk + 8 <= K) {
        const uint2* p = (const uint2*)(src + gk);
        uint2 a = p[0], b = p[1];
        *(uint2*)dst = a;
        *(uint2*)(dst + 4) = b;
    } else {
        #pragma unroll
        for (int j = 0; j < 8; j++)
            dst[j] = (rowvalid && gk + j < K) ? src[gk + j] : __float2bfloat16(0.f);
    }
}

// ---------------- MFMA bf16 GEMM: Cb[M,Ns] = A[M,K] @ Bt[Nr,K]^T + bias (+relu) ---------
// 64x64 tile, 4 waves (2x2), 2x2 mfma_f32_16x16x32_bf16 fragments.
// D layout (m89-verified): col = lane&15, row = (lane>>4)*4 + reg.
template <bool RELU>
__global__ __launch_bounds__(256) void gemm_mfma(const __hip_bfloat16* __restrict__ A,
                                                 const __hip_bfloat16* __restrict__ Bt,
                                                 const float* __restrict__ bias,
                                                 __hip_bfloat16* __restrict__ Cb,
                                                 int M, int Nr, int Ns, int K) {
    __shared__ __align__(16) __hip_bfloat16 As[64][40];
    __shared__ __align__(16) __hip_bfloat16 Bs[64][40];
    const int tid = threadIdx.x;
    const int m0 = blockIdx.y * 64, n0 = blockIdx.x * 64;
    const int lane = tid & 63;
    const int wv = tid >> 6;
    const int wm = wv >> 1, wn = wv & 1;
    const int l15 = lane & 15, lg = lane >> 4;
    const int srow = tid >> 2, sk8 = (tid & 3) * 8;
    f32x4 acc[2][2] = {};
    const int NS = (K + 31) >> 5;
    const __hip_bfloat16* arow = A + (size_t)(m0 + srow) * K;
    const bool bvalid = (n0 + srow) < Nr;
    const __hip_bfloat16* brow = Bt + (size_t)(n0 + srow) * K;

    for (int s = 0; s < NS; s++) {
        const int gk = (s << 5) + sk8;
        if (s) __syncthreads();
        stage_row8(arow, true, K, gk, &As[srow][sk8]);
        stage_row8(brow, bvalid, K, gk, &Bs[srow][sk8]);
        __syncthreads();
        bf16x8 af0 = *(const bf16x8*)&As[wm * 32 + l15][lg * 8];
        bf16x8 af1 = *(const bf16x8*)&As[wm * 32 + 16 + l15][lg * 8];
        bf16x8 bf0 = *(const bf16x8*)&Bs[wn * 32 + l15][lg * 8];
        bf16x8 bf1 = *(const bf16x8*)&Bs[wn * 32 + 16 + l15][lg * 8];
        acc[0][0] = __builtin_amdgcn_mfma_f32_16x16x32_bf16(af0, bf0, acc[0][0], 0, 0, 0);
        acc[0][1] = __builtin_amdgcn_mfma_f32_16x16x32_bf16(af0, bf1, acc[0][1], 0, 0, 0);
        acc[1][0] = __builtin_amdgcn_mfma_f32_16x16x32_bf16(af1, bf0, acc[1][0], 0, 0, 0);
        acc[1][1] = __builtin_amdgcn_mfma_f32_16x16x32_bf16(af1, bf1, acc[1][1], 0, 0, 0);
    }

    #pragma unroll
    for (int fc = 0; fc < 2; fc++) {
        int col = n0 + wn * 32 + fc * 16 + l15;
        if (col >= Ns) continue;
        float bs = (col < Nr) ? bias[col] : 0.f;
        #pragma unroll
        for (int fr = 0; fr < 2; fr++) {
            int rbase = m0 + wm * 32 + fr * 16 + lg * 4;
            #pragma unroll
            for (int r = 0; r < 4; r++) {
                float v = acc[fr][fc][r] + bs;
                if (RELU) v = fmaxf(v, 0.f);
                Cb[(size_t)(rbase + r) * Ns + col] = __float2bfloat16(v);
            }
        }
    }
}

// ---------------- DIRECT-OPERAND GEMM + residual + LayerNorm (N = 300, no LDS) ----------
// One wave owns 16 rows x all 304 cols (19 fragments); operands direct from global.
// MIX: additionally fold mix+L2-normalize: out = normalize((mx*xorig + (1-mx)*LN)*mask).
template <int NSTEP, int KSTR, int ASTR, bool MIX>
__global__ __launch_bounds__(256) void gemm_ln_direct(const __hip_bfloat16* __restrict__ A,
                                                      const __hip_bfloat16* __restrict__ Bt,
                                                      const float* __restrict__ bias,
                                                      const __hip_bfloat16* __restrict__ Res,
                                                      const float* __restrict__ g,
                                                      const float* __restrict__ beta,
                                                      __hip_bfloat16* __restrict__ Y,
                                                      const __hip_bfloat16* __restrict__ Xorig,
                                                      const float* __restrict__ mall,
                                                      const float* __restrict__ mixer) {
    const int tid = threadIdx.x;
    const int wv = tid >> 6;
    const int lane = tid & 63;
    const int l15 = lane & 15, lg = lane >> 4;
    const int m0 = blockIdx.x * 64 + wv * 16;

    f32x4 acc[19];
    #pragma unroll
    for (int fc = 0; fc < 19; fc++) acc[fc] = (f32x4){0.f, 0.f, 0.f, 0.f};

    #pragma unroll
    for (int ks = 0; ks < NSTEP; ks++) {
        const int kb = ks * 32 + lg * 8;
        bf16x8 af = *(const bf16x8*)(A + (size_t)(m0 + l15) * ASTR + kb);
        #pragma unroll
        for (int fc = 0; fc < 19; fc++) {
            bf16x8 bf = *(const bf16x8*)(Bt + (size_t)(fc * 16 + l15) * KSTR + kb);
            acc[fc] = __builtin_amdgcn_mfma_f32_16x16x32_bf16(af, bf, acc[fc], 0, 0, 0);
        }
    }

    float rs[4] = {0.f, 0.f, 0.f, 0.f};
    #pragma unroll
    for (int fc = 0; fc < 19; fc++) {
        int col = fc * 16 + l15;
        bool valid = col < EMB;
        float bs = valid ? bias[col] : 0.f;
        #pragma unroll
        for (int r = 0; r < 4; r++) {
            float v = 0.f;
            if (valid) v = acc[fc][r] + bs + bf2f(Res[(size_t)(m0 + lg * 4 + r) * EMB + col]);
            acc[fc][r] = v;
            rs[r] += v;
        }
    }
    #pragma unroll
    for (int r = 0; r < 4; r++)
        #pragma unroll
        for (int off = 1; off < 16; off <<= 1)
            rs[r] += __shfl_xor(rs[r], off);
    float mean[4], invv[4];
    #pragma unroll
    for (int r = 0; r < 4; r++) mean[r] = rs[r] * (1.f / EMB);

    float rq[4] = {0.f, 0.f, 0.f, 0.f};
    #pragma unroll
    for (int fc = 0; fc < 19; fc++) {
        int col = fc * 16 + l15;
        if (col < EMB) {
            #pragma unroll
            for (int r = 0; r < 4; r++) {
                float d = acc[fc][r] - mean[r];
                rq[r] += d * d;
            }
        }
    }
    #pragma unroll
    for (int r = 0; r < 4; r++) {
        #pragma unroll
        for (int off = 1; off < 16; off <<= 1)
            rq[r] += __shfl_xor(rq[r], off);
        float stdv = sqrtf(rq[r] * (1.f / (EMB - 1)));
        invv[r] = 1.f / (stdv + 1e-6f);
    }

    if (!MIX) {
        #pragma unroll
        for (int fc = 0; fc < 19; fc++) {
            int col = fc * 16 + l15;
            if (col >= EMB) continue;
            float gv = g[col], bv = beta[col];
            #pragma unroll
            for (int r = 0; r < 4; r++) {
                float y = gv * (acc[fc][r] - mean[r]) * invv[r] + bv;
                Y[(size_t)(m0 + lg * 4 + r) * EMB + col] = __float2bfloat16(y);
            }
        }
    } else {
        // fold: v = (mx*xorig + (1-mx)*ln)*mval; out = v / (||v|| + 1e-13)
        float mx = mixer[0];
        float mval[4];
        #pragma unroll
        for (int r = 0; r < 4; r++) mval[r] = mall[m0 + lg * 4 + r];
        float sq[4] = {0.f, 0.f, 0.f, 0.f};
        #pragma unroll
        for (int fc = 0; fc < 19; fc++) {
            int col = fc * 16 + l15;
            bool valid = col < EMB;
            float gv = valid ? g[col] : 0.f;
            float bv = valid ? beta[col] : 0.f;
            #pragma unroll
            for (int r = 0; r < 4; r++) {
                float v = 0.f;
                if (valid) {
                    float ln = gv * (acc[fc][r] - mean[r]) * invv[r] + bv;
                    float xo = bf2f(Xorig[(size_t)(m0 + lg * 4 + r) * EMB + col]);
                    v = (mx * xo + (1.f - mx) * ln) * mval[r];
                }
                acc[fc][r] = v;
                sq[r] += v * v;
            }
        }
        #pragma unroll
        for (int r = 0; r < 4; r++) {
            #pragma unroll
            for (int off = 1; off < 16; off <<= 1)
                sq[r] += __shfl_xor(sq[r], off);
            sq[r] = 1.f / (sqrtf(sq[r]) + 1e-13f);
        }
        #pragma unroll
        for (int fc = 0; fc < 19; fc++) {
            int col = fc * 16 + l15;
            if (col >= EMB) continue;
            #pragma unroll
            for (int r = 0; r < 4; r++) {
                Y[(size_t)(m0 + lg * 4 + r) * EMB + col] = __float2bfloat16(acc[fc][r] * sq[r]);
            }
        }
    }
}

// ---------------- batched MFMA cos GEMM: Cos[b] = Qn[b] (64xK) @ Dn[b] (512xK)^T (fp32 out)
__global__ __launch_bounds__(256) void cos_mfma(const __hip_bfloat16* __restrict__ Qn,
                                                const __hip_bfloat16* __restrict__ Dn,
                                                float* __restrict__ Cos) {
    __shared__ __align__(16) __hip_bfloat16 As[64][40];
    __shared__ __align__(16) __hip_bfloat16 Bs[64][40];
    const int b = blockIdx.y;
    const int n0 = blockIdx.x * 64;
    const int tid = threadIdx.x;
    const int lane = tid & 63;
    const int wv = tid >> 6;
    const int wm = wv >> 1, wn = wv & 1;
    const int l15 = lane & 15, lg = lane >> 4;
    const int srow = tid >> 2, sk8 = (tid & 3) * 8;
    f32x4 acc[2][2] = {};
    const int NS = (EMB + 31) >> 5;   // 10
    const __hip_bfloat16* arow = Qn + ((size_t)b * LQ + srow) * EMB;
    const __hip_bfloat16* brow = Dn + ((size_t)b * LD + n0 + srow) * EMB;

    for (int s = 0; s < NS; s++) {
        const int gk = (s << 5) + sk8;
        if (s) __syncthreads();
        stage_row8(arow, true, EMB, gk, &As[srow][sk8]);
        stage_row8(brow, true, EMB, gk, &Bs[srow][sk8]);
        __syncthreads();
        bf16x8 af0 = *(const bf16x8*)&As[wm * 32 + l15][lg * 8];
        bf16x8 af1 = *(const bf16x8*)&As[wm * 32 + 16 + l15][lg * 8];
        bf16x8 bf0 = *(const bf16x8*)&Bs[wn * 32 + l15][lg * 8];
        bf16x8 bf1 = *(const bf16x8*)&Bs[wn * 32 + 16 + l15][lg * 8];
        acc[0][0] = __builtin_amdgcn_mfma_f32_16x16x32_bf16(af0, bf0, acc[0][0], 0, 0, 0);
        acc[0][1] = __builtin_amdgcn_mfma_f32_16x16x32_bf16(af0, bf1, acc[0][1], 0, 0, 0);
        acc[1][0] = __builtin_amdgcn_mfma_f32_16x16x32_bf16(af1, bf0, acc[1][0], 0, 0, 0);
        acc[1][1] = __builtin_amdgcn_mfma_f32_16x16x32_bf16(af1, bf1, acc[1][1], 0, 0, 0);
    }

    float* cb = Cos + (size_t)b * LQ * LD;
    #pragma unroll
    for (int fc = 0; fc < 2; fc++) {
        int col = n0 + wn * 32 + fc * 16 + l15;
        #pragma unroll
        for (int fr = 0; fr < 2; fr++) {
            int rbase = wm * 32 + fr * 16 + lg * 4;
            #pragma unroll
            for (int r = 0; r < 4; r++) {
                cb[(size_t)(rbase + r) * LD + col] = acc[fr][fc][r];
            }
        }
    }
}

// ---------------- attention body (templated), smem carved by caller ----------------
template <int T, int RPB, int KS>
__device__ __forceinline__ void attn_body(const __hip_bfloat16* __restrict__ cseg,
                                          const float* __restrict__ mask,
                                          __hip_bfloat16* __restrict__ oseg,
                                          int bh, int rb, char* smem) {
    constexpr int BLK = 512;
    float4* Ks = (float4*)smem;
    float4* Vs = Ks + T;
    float* part = (float*)(Vs + T);
    float* nmask_s = part + RPB * 5 * (KS - 1);
    const int b = bh / NH, h = bh % NH;
    const int tid = threadIdx.x;
    const __hip_bfloat16* base = cseg + (size_t)b * T * 96;

    if (tid == 0) *nmask_s = 0.f;
    __syncthreads();
    float lnm = 0.f;
    for (int j = tid; j < T; j += BLK) {
        float m = mask[b * T + j];
        float4 kv = bf4_to_f4(base + (size_t)j * 96 + ATTD + h * 4);
        float4 vv = bf4_to_f4(base + (size_t)j * 96 + 2 * ATTD + h * 4);
        kv.x *= m; kv.y *= m; kv.z *= m; kv.w *= m;
        vv.x *= m; vv.y *= m; vv.z *= m; vv.w *= m;
        Ks[j] = kv;
        Vs[j] = vv;
        lnm += 1.f - m;
    }
    lnm = wave_sum(lnm);
    if ((tid & 63) == 0 && lnm != 0.f) atomicAdd(nmask_s, lnm);
    __syncthreads();

    const int r = rb * RPB + (tid % RPB);
    const int ks = tid / RPB;
    const float inv_scale = 0.16439898730535729f;  // 1/sqrt(37)
    float4 qv = bf4_to_f4(base + (size_t)r * 96 + h * 4);
    qv.x *= inv_scale; qv.y *= inv_scale; qv.z *= inv_scale; qv.w *= inv_scale;

    float Sall = 0.f, ox = 0.f, oy = 0.f, oz = 0.f, ow = 0.f;
    constexpr int KC = T / KS;
    const int k0 = ks * KC;
    #pragma unroll 4
    for (int k = k0; k < k0 + KC; k++) {
        float4 kv = Ks[k];
        float4 vv = Vs[k];
        float s = fmaf(qv.x, kv.x, fmaf(qv.y, kv.y, fmaf(qv.z, kv.z, qv.w * kv.w)));
        float e = __expf(s);
        Sall += e;
        ox = fmaf(e, vv.x, ox);
        oy = fmaf(e, vv.y, oy);
        oz = fmaf(e, vv.z, oz);
        ow = fmaf(e, vv.w, ow);
    }
    if (ks > 0) {
        float* p = &part[((ks - 1) * RPB + (tid % RPB)) * 5];
        p[0] = Sall; p[1] = ox; p[2] = oy; p[3] = oz; p[4] = ow;
    }
    __syncthreads();
    if (ks == 0) {
        #pragma unroll
        for (int s2 = 0; s2 < KS - 1; s2++) {
            const float* p = &part[(s2 * RPB + r - rb * RPB) * 5];
            Sall += p[0]; ox += p[1]; oy += p[2]; oz += p[3]; ow += p[4];
        }
        float Sm = Sall - *nmask_s;
        float inv = 1.f / (Sm + 1e-13f * Sall);
        __hip_bfloat16* op = oseg + (size_t)(b * T + r) * ATTD + h * 4;
        op[0] = __float2bfloat16(ox * inv);
        op[1] = __float2bfloat16(oy * inv);
        op[2] = __float2bfloat16(oz * inv);
        op[3] = __float2bfloat16(ow * inv);
    }
}

// ---------------- merged q+d attention: blocks [0,256) = q, [256,1280) = d ----------------
__global__ __launch_bounds__(512) void attn_both(const __hip_bfloat16* __restrict__ cbf,
                                                 const float* __restrict__ mask_q,
                                                 const float* __restrict__ mask_d,
                                                 __hip_bfloat16* __restrict__ o32) {
    __shared__ __align__(16) char smem[24576];
    int blk = blockIdx.x;
    if (blk < BATCH * NH) {
        attn_body<LQ, 64, 8>(cbf, mask_q, o32, blk, 0, smem);
    } else {
        int bid = blk - BATCH * NH;
        attn_body<LD, 128, 4>(cbf + (size_t)MQ * 96, mask_d, o32 + (size_t)MQ * ATTD,
                              bid >> 2, bid & 3, smem);
    }
}

// ---------------- kernel pooling with grouped exp-recurrence ----------------
__global__ __launch_bounds__(256) void pool_kernel(const float* __restrict__ Cos,
                                                   const float* __restrict__ mask_q,
                                                   const float* __restrict__ mask_d,
                                                   const float* __restrict__ nn_scaler,
                                                   float* __restrict__ lp) {
    int wid = (blockIdx.x * 256 + threadIdx.x) >> 6;
    int lane = threadIdx.x & 63;
    int b = wid >> 6, qi = wid & 63;
    const float* crow = Cos + ((size_t)b * LQ + qi) * LD;
    const float* md = mask_d + b * LD;
    float acc[NK];
    #pragma unroll
    for (int k = 0; k < NK; k++) acc[k] = 0.f;
    #pragma unroll
    for (int rr = 0; rr < LD / 64; rr++) {
        int dj = rr * 64 + lane;
        float m = md[dj];
        if (m != 0.f) {
            float cv = crow[dj];
            float d0 = cv - 1.0f;
            acc[0] += __expf(d0 * d0 * -500000.0f);
            #pragma unroll
            for (int g = 0; g < 4; g++) {
                float mu_a = 0.95f - 0.5f * g;
                float dc = cv - mu_a;
                float t = __expf(dc * dc * -50.0f);
                float r = __expf(fmaf(-10.0f, dc, -0.5f));
                #pragma unroll
                for (int j = 0; j < 5; j++) {
                    acc[1 + 5 * g + j] += t;
                    t *= r;
                    r *= 0.36787944117144233f;   // e^-1
                }
            }
        }
    }
    float mq = mask_q[b * LQ + qi];
    float ns = nn_scaler[0];
    #pragma unroll
    for (int k = 0; k < NK; k++) {
        float s = wave_sum(acc[k]);
        if (lane == 0) lp[((size_t)b * LQ + qi) * NK + k] = log2f(fmaxf(s, 1e-10f)) * ns * mq;
    }
}

// ---------------- final: out[b] = sum_k dense_w[k] * sum_qi lp[b,qi,k] ----------------
__global__ void final_kernel(const float* __restrict__ lp, const float* __restrict__ dense_w,
                             float* __restrict__ out) {
    int b = blockIdx.x;
    int t = threadIdx.x;  // 64 threads
    float s = 0.f;
    if (t < NK) {
        for (int qi = 0; qi < LQ; qi++) s += lp[((size_t)b * LQ + qi) * NK + t];
        s *= dense_w[t];
    }
    s = wave_sum(s);
    if (t == 0) out[b] = s;
}

extern "C" void kernel_launch(void* const* d_in, const int* in_sizes, int n_in,
                              void* d_out, int out_size, void* d_ws, size_t ws_size,
                              hipStream_t stream) {
    (void)in_sizes; (void)n_in; (void)out_size; (void)ws_size;
    const float* q_embed  = (const float*)d_in[0];
    const float* d_embed  = (const float*)d_in[1];
    const float* mask_q   = (const float*)d_in[2];
    const float* mask_d   = (const float*)d_in[3];
    const float* mixer    = (const float*)d_in[4];
    const float* nn_scaler= (const float*)d_in[5];
    const float* ff_w1    = (const float*)d_in[6];
    const float* ff_b1    = (const float*)d_in[7];
    const float* ff_w2    = (const float*)d_in[8];
    const float* ff_b2    = (const float*)d_in[9];
    const float* ln1_g    = (const float*)d_in[10];
    const float* ln1_b    = (const float*)d_in[11];
    const float* att_w    = (const float*)d_in[12];
    const float* att_b    = (const float*)d_in[13];
    const float* out_w    = (const float*)d_in[14];
    const float* out_b    = (const float*)d_in[15];
    const float* ln2_g    = (const float*)d_in[16];
    const float* ln2_b    = (const float*)d_in[17];
    const float* dense_w  = (const float*)d_in[18];
    float* out = (float*)d_out;

    // ---------------- workspace layout ----------------
    float* ws   = (float*)d_ws;
    float* cosb = ws;                         // 32*64*512 = 1,048,576 fp32
    float* lp   = cosb + 1048576;             // 43,008
    float* mall = lp + 43008;                 // 18,432
    __hip_bfloat16* xbf   = (__hip_bfloat16*)(mall + MALL);   // MALL*EMB masked embeddings
    __hip_bfloat16* xcbf  = xbf  + (size_t)MALL * EMB;        // layer-0 output
    __hip_bfloat16* qdn   = xcbf + (size_t)MALL * EMB;        // layer-1 fused LN2+mixnorm out
    __hip_bfloat16* hbf   = qdn  + (size_t)MALL * EMB;        // LN1 out
    __hip_bfloat16* t1bf  = hbf  + (size_t)MALL * EMB;        // MALL*128 (stride-128, zero-pad)
    __hip_bfloat16* cbf   = t1bf + (size_t)MALL * 128;        // MALL*96
    __hip_bfloat16* o32bf = cbf  + (size_t)MALL * 96;         // MALL*ATTD
    __hip_bfloat16* w1t   = o32bf + (size_t)MALL * ATTD;      // 2*100*300
    __hip_bfloat16* w2t   = w1t + 2 * FFH * EMB;              // 2*320*128 (padded)
    __hip_bfloat16* awt   = w2t + 2 * 320 * 128;              // 2*96*300
    __hip_bfloat16* owt   = awt + 2 * 96 * EMB;               // 2*320*32 (padded)

    // 0. fused prep: masked embeddings (float4 reads) + masks + all weights
    const int PREP_N = MALL * (EMB / 4) + 2 * EMB * FFH + 2 * 320 * 128 + 2 * EMB * 96 + 2 * 320 * 32;
    prep_all<<<(PREP_N + 255) / 256, 256, 0, stream>>>(
        q_embed, d_embed, mask_q, mask_d, ff_w1, ff_w2, att_w, out_w,
        xbf, mall, w1t, w2t, awt, owt);

    // 1. merged encoder; layer-1 OUT+LN2 also folds mix+normalize
    const __hip_bfloat16* xcur = xbf;
    for (int l = 0; l < 2; l++) {
        // FF1: relu(x @ w1 + b1) -> t1bf (stride 128, cols 100..127 zeroed)
        gemm_mfma<true><<<dim3(2, MALL / 64), 256, 0, stream>>>(
            xcur, w1t + (size_t)l * FFH * EMB, ff_b1 + l * FFH, t1bf, MALL, FFH, 128, EMB);
        // FF2 + residual(x) + LN1 -> hbf   (direct, K=128 padded)
        gemm_ln_direct<4, 128, 128, false><<<MALL / 64, 256, 0, stream>>>(
            t1bf, w2t + (size_t)l * 320 * 128, ff_b2 + l * EMB, xcur,
            ln1_g + l * EMB, ln1_b + l * EMB, hbf, nullptr, nullptr, nullptr);
        // ATT: h @ att_w + att_b -> cbf
        gemm_mfma<false><<<dim3(2, MALL / 64), 256, 0, stream>>>(
            hbf, awt + (size_t)l * 96 * EMB, att_b + l * 96, cbf, MALL, 96, 96, EMB);
        // attention (q + d merged) -> o32bf
        attn_both<<<BATCH * NH + BATCH * NH * (LD / 128), 512, 0, stream>>>(
            cbf, mask_q, mask_d, o32bf);
        // OUT + residual(h) + LN2 (-> xcbf for l=0; + mix/normalize -> qdn for l=1)
        if (l == 0) {
            gemm_ln_direct<1, 32, 32, false><<<MALL / 64, 256, 0, stream>>>(
                o32bf, owt, out_b, hbf, ln2_g, ln2_b, xcbf, nullptr, nullptr, nullptr);
            xcur = xcbf;
        } else {
            gemm_ln_direct<1, 32, 32, true><<<MALL / 64, 256, 0, stream>>>(
                o32bf, owt + (size_t)320 * 32, out_b + EMB, hbf,
                ln2_g + EMB, ln2_b + EMB, qdn, xbf, mall, mixer);
        }
    }

    // 2. cosine matrix via MFMA -> cosb
    cos_mfma<<<dim3(LD / 64, BATCH), 256, 0, stream>>>(qdn, qdn + (size_t)MQ * EMB, cosb);

    // 3. kernel pooling (grouped exp-recurrence)
    pool_kernel<<<(BATCH * LQ) / 4, 256, 0, stream>>>(cosb, mask_q, mask_d, nn_scaler, lp);

    // 4. final projection
    final_kernel<<<BATCH, 64, 0, stream>>>(lp, dense_w, out);
}